// Round 1
// baseline (4443.507 us; speedup 1.0000x reference)
//
#include <hip/hip_runtime.h>

#define NUSR 100000
#define NITM 50000
#define NEDG 1000000
#define NPRED 250000
#define DD 64
#define DD2 128
#define MSG_EPS 1e-7f
#define BN_EPS 1e-5f

// ---------------- edge pass 1: segment max (positive floats via uint atomicMax) ----
__global__ __launch_bounds__(256) void edge_max_k(
    const float* __restrict__ xsrc, const int* __restrict__ src_idx,
    const int* __restrict__ dst_idx, unsigned int* __restrict__ mx)
{
    int idx = blockIdx.x * 256 + threadIdx.x;
    int e = idx >> 6, d = idx & 63;
    if (e >= NEDG) return;
    int s = src_idx[e], t = dst_idx[e];
    float v = fmaxf(xsrc[(size_t)s * DD + d], 0.f) + MSG_EPS;
    atomicMax(&mx[(size_t)t * DD + d], __float_as_uint(v));
}

// ---------------- edge pass 2: accumulate den = sum(exp), num = sum(exp*m) --------
__global__ __launch_bounds__(256) void edge_sum_k(
    const float* __restrict__ xsrc, const int* __restrict__ src_idx,
    const int* __restrict__ dst_idx, const unsigned int* __restrict__ mx,
    float* __restrict__ den, float* __restrict__ num)
{
    int idx = blockIdx.x * 256 + threadIdx.x;
    int e = idx >> 6, d = idx & 63;
    if (e >= NEDG) return;
    int s = src_idx[e], t = dst_idx[e];
    float v = fmaxf(xsrc[(size_t)s * DD + d], 0.f) + MSG_EPS;
    float m = __uint_as_float(mx[(size_t)t * DD + d]);
    float ex = __expf(v - m);
    atomicAdd(&den[(size_t)t * DD + d], ex);
    atomicAdd(&num[(size_t)t * DD + d], ex * v);
}

// ---------------- GEMM1: h1 = (agg + x_dst) @ W1 + b1, accumulate BN stats -------
__global__ __launch_bounds__(256) void gemm1_bn_k(
    const float* __restrict__ num, const float* __restrict__ den,
    const float* __restrict__ xdst, const float* __restrict__ W1,
    const float* __restrict__ b1, float* __restrict__ h1,
    double* __restrict__ gsum, double* __restrict__ gsq, int N)
{
    __shared__ float sW[DD * DD2];          // 32 KB
    __shared__ float sx[32][DD + 1];        // padded
    __shared__ float sred[2][8][DD2];       // 8 KB

    int t = threadIdx.x;
    for (int i = t; i < DD * DD2; i += 256) sW[i] = W1[i];
    int r0 = blockIdx.x * 32;
    for (int i = t; i < 32 * DD; i += 256) {
        int rr = i >> 6, k = i & 63, r = r0 + rr;
        float v = 0.f;
        if (r < N) {
            float dn = den[(size_t)r * DD + k];
            float ag = dn > 0.f ? num[(size_t)r * DD + k] / dn : 0.f;
            v = ag + xdst[(size_t)r * DD + k];
        }
        sx[rr][k] = v;
    }
    __syncthreads();

    int tx = t & 31, ty = t >> 5;           // 32 col-groups x 8 row-groups
    float acc[4][4];
    #pragma unroll
    for (int i = 0; i < 4; i++)
        #pragma unroll
        for (int j = 0; j < 4; j++) acc[i][j] = 0.f;

    #pragma unroll 4
    for (int k = 0; k < DD; k++) {
        float4 w = ((const float4*)(sW + k * DD2))[tx];
        #pragma unroll
        for (int i = 0; i < 4; i++) {
            float xv = sx[ty * 4 + i][k];
            acc[i][0] = fmaf(xv, w.x, acc[i][0]);
            acc[i][1] = fmaf(xv, w.y, acc[i][1]);
            acc[i][2] = fmaf(xv, w.z, acc[i][2]);
            acc[i][3] = fmaf(xv, w.w, acc[i][3]);
        }
    }

    float4 bb = ((const float4*)b1)[tx];
    float ps[4] = {0,0,0,0}, pq[4] = {0,0,0,0};
    #pragma unroll
    for (int i = 0; i < 4; i++) {
        int r = r0 + ty * 4 + i;
        if (r < N) {
            float4 hv;
            hv.x = acc[i][0] + bb.x; hv.y = acc[i][1] + bb.y;
            hv.z = acc[i][2] + bb.z; hv.w = acc[i][3] + bb.w;
            ((float4*)(h1 + (size_t)r * DD2))[tx] = hv;
            ps[0] += hv.x; pq[0] += hv.x * hv.x;
            ps[1] += hv.y; pq[1] += hv.y * hv.y;
            ps[2] += hv.z; pq[2] += hv.z * hv.z;
            ps[3] += hv.w; pq[3] += hv.w * hv.w;
        }
    }
    #pragma unroll
    for (int j = 0; j < 4; j++) {
        sred[0][ty][tx * 4 + j] = ps[j];
        sred[1][ty][tx * 4 + j] = pq[j];
    }
    __syncthreads();
    if (t < DD2) {
        float s = 0.f, q = 0.f;
        #pragma unroll
        for (int y = 0; y < 8; y++) { s += sred[0][y][t]; q += sred[1][y][t]; }
        atomicAdd(&gsum[t], (double)s);
        atomicAdd(&gsq[t],  (double)q);
    }
}

// ---------------- BN finalize: per-column scale/shift -----------------------------
__global__ void bn_fin_k(const double* __restrict__ gsum, const double* __restrict__ gsq,
                         const float* __restrict__ gamma, const float* __restrict__ beta,
                         float2* __restrict__ ss, int N)
{
    int c = threadIdx.x;
    double mean = gsum[c] / (double)N;
    double var  = gsq[c] / (double)N - mean * mean;
    float inv = (float)(1.0 / sqrt(var + (double)BN_EPS));
    float sc = gamma[c] * inv;
    ss[c] = make_float2(sc, beta[c] - (float)mean * sc);
}

// ---------------- GEMM2: xnew = relu( relu(bn(h1)) @ W2 + b2 ) --------------------
__global__ __launch_bounds__(256) void gemm2_k(
    const float* __restrict__ h1, const float2* __restrict__ ss,
    const float* __restrict__ W2, const float* __restrict__ b2,
    float* __restrict__ xnew, int N)
{
    __shared__ float sW[DD2 * DD];          // 32 KB
    __shared__ float sx[32][DD2 + 1];       // 16.1 KB

    int t = threadIdx.x;
    for (int i = t; i < DD2 * DD; i += 256) sW[i] = W2[i];
    int r0 = blockIdx.x * 32;
    for (int i = t; i < 32 * DD2; i += 256) {
        int rr = i >> 7, k = i & 127, r = r0 + rr;
        float v = 0.f;
        if (r < N) {
            float2 sc = ss[k];
            v = fmaxf(fmaf(h1[(size_t)r * DD2 + k], sc.x, sc.y), 0.f);
        }
        sx[rr][k] = v;
    }
    __syncthreads();

    int tx = t & 15, ty = t >> 4;           // 16 col-groups x 16 row-groups (2 rows)
    float acc[2][4];
    #pragma unroll
    for (int i = 0; i < 2; i++)
        #pragma unroll
        for (int j = 0; j < 4; j++) acc[i][j] = 0.f;

    #pragma unroll 4
    for (int k = 0; k < DD2; k++) {
        float4 w = ((const float4*)(sW + k * DD))[tx];
        #pragma unroll
        for (int i = 0; i < 2; i++) {
            float xv = sx[ty * 2 + i][k];
            acc[i][0] = fmaf(xv, w.x, acc[i][0]);
            acc[i][1] = fmaf(xv, w.y, acc[i][1]);
            acc[i][2] = fmaf(xv, w.z, acc[i][2]);
            acc[i][3] = fmaf(xv, w.w, acc[i][3]);
        }
    }
    float4 bb = ((const float4*)b2)[tx];
    #pragma unroll
    for (int i = 0; i < 2; i++) {
        int r = r0 + ty * 2 + i;
        if (r < N) {
            float4 o;
            o.x = fmaxf(acc[i][0] + bb.x, 0.f);
            o.y = fmaxf(acc[i][1] + bb.y, 0.f);
            o.z = fmaxf(acc[i][2] + bb.z, 0.f);
            o.w = fmaxf(acc[i][3] + bb.w, 0.f);
            ((float4*)(xnew + (size_t)r * DD))[tx] = o;
        }
    }
}

// ---------------- decoder: dot(xu[pu], xi[pi]) ------------------------------------
__global__ __launch_bounds__(256) void decode_k(
    const float* __restrict__ xu, const float* __restrict__ xi,
    const int* __restrict__ pu, const int* __restrict__ pi,
    float* __restrict__ out)
{
    int idx = blockIdx.x * 256 + threadIdx.x;
    int b = idx >> 4, lane = idx & 15;
    if (b >= NPRED) return;
    int u = pu[b], it = pi[b];
    float4 a = ((const float4*)(xu + (size_t)u * DD))[lane];
    float4 c = ((const float4*)(xi + (size_t)it * DD))[lane];
    float s = a.x * c.x + a.y * c.y + a.z * c.z + a.w * c.w;
    #pragma unroll
    for (int off = 8; off; off >>= 1) s += __shfl_down(s, off, 16);
    if (lane == 0) out[b] = s;
}

// ---------------- host-side conv driver -------------------------------------------
static void run_conv(const float* xsrc, const float* xdst,
                     const int* sidx, const int* didx, int Ndst,
                     const float* W1p, const float* b1p,
                     const float* gp, const float* bp,
                     const float* W2p, const float* b2p,
                     float* scratch, float* h1, double* gsum, double* gsq,
                     float2* ss, float* xnew, hipStream_t stream)
{
    float* mx  = scratch;
    float* den = scratch + (size_t)Ndst * DD;
    float* num = scratch + 2ull * Ndst * DD;
    hipMemsetAsync(scratch, 0, 3ull * Ndst * DD * sizeof(float), stream);
    hipMemsetAsync(gsum, 0, 2 * DD2 * sizeof(double), stream); // gsum|gsq contiguous

    int eg = (NEDG * 64) / 256;
    edge_max_k<<<eg, 256, 0, stream>>>(xsrc, sidx, didx, (unsigned int*)mx);
    edge_sum_k<<<eg, 256, 0, stream>>>(xsrc, sidx, didx, (const unsigned int*)mx, den, num);

    int g1 = (Ndst + 31) / 32;
    gemm1_bn_k<<<g1, 256, 0, stream>>>(num, den, xdst, W1p, b1p, h1, gsum, gsq, Ndst);
    bn_fin_k<<<1, DD2, 0, stream>>>(gsum, gsq, gp, bp, ss, Ndst);
    gemm2_k<<<g1, 256, 0, stream>>>(h1, ss, W2p, b2p, xnew, Ndst);
}

extern "C" void kernel_launch(void* const* d_in, const int* in_sizes, int n_in,
                              void* d_out, int out_size, void* d_ws, size_t ws_size,
                              hipStream_t stream)
{
    const float* x_user = (const float*)d_in[0];
    const float* x_item = (const float*)d_in[1];
    const float* W1    = (const float*)d_in[2];   // [3][2][64][128]
    const float* b1    = (const float*)d_in[3];   // [3][2][128]
    const float* gamma = (const float*)d_in[4];   // [3][2][128]
    const float* beta  = (const float*)d_in[5];   // [3][2][128]
    const float* W2    = (const float*)d_in[6];   // [3][2][128][64]
    const float* b2    = (const float*)d_in[7];   // [3][2][64]
    const int* edge = (const int*)d_in[8];        // [2][E]
    const int* pred = (const int*)d_in[9];        // [2][B]
    float* out = (float*)d_out;

    const int* u_idx = edge;          // row 0: user (src of u->i)
    const int* i_idx = edge + NEDG;   // row 1: item

    // workspace layout (bump allocator), ~205 MB total
    char* p = (char*)d_ws;
    float* scratch = (float*)p; p += 3ull * NUSR * DD * sizeof(float);   // 76.8 MB
    float* h1      = (float*)p; p += (size_t)NUSR * DD2 * sizeof(float); // 51.2 MB
    double* gsum   = (double*)p; p += DD2 * sizeof(double);
    double* gsq    = (double*)p; p += DD2 * sizeof(double);
    float2* ss     = (float2*)p; p += DD2 * sizeof(float2);
    float* xu_buf[2]; float* xi_buf[2];
    xu_buf[0] = (float*)p; p += (size_t)NUSR * DD * sizeof(float);
    xu_buf[1] = (float*)p; p += (size_t)NUSR * DD * sizeof(float);
    xi_buf[0] = (float*)p; p += (size_t)NITM * DD * sizeof(float);
    xi_buf[1] = (float*)p; p += (size_t)NITM * DD * sizeof(float);

    const float* cu = x_user;
    const float* ci = x_item;
    for (int l = 0; l < 3; l++) {
        size_t o0 = (size_t)l * 2 + 0;   // user->item conv params
        size_t o1 = (size_t)l * 2 + 1;   // item->user conv params
        float* ni = xi_buf[l & 1];
        float* nu = xu_buf[l & 1];
        // new_i: src=user, dst=item
        run_conv(cu, ci, u_idx, i_idx, NITM,
                 W1 + o0 * DD * DD2, b1 + o0 * DD2, gamma + o0 * DD2, beta + o0 * DD2,
                 W2 + o0 * DD2 * DD, b2 + o0 * DD,
                 scratch, h1, gsum, gsq, ss, ni, stream);
        // new_u: src=item, dst=user
        run_conv(ci, cu, i_idx, u_idx, NUSR,
                 W1 + o1 * DD * DD2, b1 + o1 * DD2, gamma + o1 * DD2, beta + o1 * DD2,
                 W2 + o1 * DD2 * DD, b2 + o1 * DD,
                 scratch, h1, gsum, gsq, ss, nu, stream);
        cu = nu; ci = ni;
    }

    decode_k<<<(NPRED * 16) / 256, 256, 0, stream>>>(cu, ci, pred, pred + NPRED, out);
}

// Round 2
// 1692.195 us; speedup vs baseline: 2.6259x; 2.6259x over previous
//
#include <hip/hip_runtime.h>

#define NUSR 100000
#define NITM 50000
#define NEDG 1000000
#define NPRED 250000
#define DD 64
#define DD2 128
#define MSG_EPS 1e-7f
#define BN_EPS 1e-5f
#define SCAN_B 1024

// ================= CSR build (once per call; edges are layer-invariant) ==========

__global__ __launch_bounds__(256) void count_k(
    const int* __restrict__ u_idx, const int* __restrict__ i_idx,
    int* __restrict__ deg_u, int* __restrict__ deg_i)
{
    int e = blockIdx.x * 256 + threadIdx.x;
    if (e >= NEDG) return;
    atomicAdd(&deg_i[i_idx[e]], 1);
    atomicAdd(&deg_u[u_idx[e]], 1);
}

// inclusive scan per 1024-chunk; block totals to bsum
__global__ __launch_bounds__(SCAN_B) void scan1_k(
    const int* __restrict__ deg, int* __restrict__ partial, int* __restrict__ bsum, int n)
{
    __shared__ int s[SCAN_B];
    int tid = threadIdx.x;
    int i = blockIdx.x * SCAN_B + tid;
    s[tid] = (i < n) ? deg[i] : 0;
    __syncthreads();
    for (int off = 1; off < SCAN_B; off <<= 1) {
        int t = (tid >= off) ? s[tid - off] : 0;
        __syncthreads();
        s[tid] += t;
        __syncthreads();
    }
    if (i < n) partial[i] = s[tid];
    if (tid == SCAN_B - 1) bsum[blockIdx.x] = s[tid];
}

// exclusive scan of block sums (nb <= 128), single block
__global__ __launch_bounds__(128) void scan2_k(int* __restrict__ bsum, int nb)
{
    __shared__ int s[128];
    int tid = threadIdx.x;
    s[tid] = (tid < nb) ? bsum[tid] : 0;
    __syncthreads();
    for (int off = 1; off < 128; off <<= 1) {
        int t = (tid >= off) ? s[tid - off] : 0;
        __syncthreads();
        s[tid] += t;
        __syncthreads();
    }
    if (tid < nb) bsum[tid] = (tid == 0) ? 0 : s[tid - 1];
}

// rowptr (exclusive) + cursor init; rowptr[n] = E
__global__ __launch_bounds__(SCAN_B) void scan3_k(
    const int* __restrict__ deg, const int* __restrict__ partial,
    const int* __restrict__ bsum, int* __restrict__ rowptr, int* __restrict__ cursor, int n)
{
    int i = blockIdx.x * SCAN_B + threadIdx.x;
    if (i < n) {
        int rs = partial[i] - deg[i] + bsum[blockIdx.x];
        rowptr[i] = rs;
        cursor[i] = rs;
    }
    if (i == 0) rowptr[n] = NEDG;
}

__global__ __launch_bounds__(256) void scatter_k(
    const int* __restrict__ u_idx, const int* __restrict__ i_idx,
    int* __restrict__ cur_i, int* __restrict__ cur_u,
    int* __restrict__ csr_i, int* __restrict__ csr_u)
{
    int e = blockIdx.x * 256 + threadIdx.x;
    if (e >= NEDG) return;
    int u = u_idx[e], it = i_idx[e];
    int p = atomicAdd(&cur_i[it], 1); csr_i[p] = u;   // item's incident users
    int q = atomicAdd(&cur_u[u], 1);  csr_u[q] = it;  // user's incident items
}

// ================= aggregation: one wave per dst row, online softmax =============
__global__ __launch_bounds__(256) void agg_k(
    const float* __restrict__ xsrc, const float* __restrict__ xdst,
    const int* __restrict__ rowptr, const int* __restrict__ csr,
    float* __restrict__ hin, int N)
{
    int idx = blockIdx.x * 256 + threadIdx.x;
    int w = idx >> 6, lane = idx & 63;
    if (w >= N) return;
    int beg = rowptr[w], end = rowptr[w + 1];
    float mx = -1e30f, den = 0.f, num = 0.f;
    for (int j = beg; j < end; j++) {
        int s = csr[j];
        float v = fmaxf(xsrc[(size_t)s * DD + lane], 0.f) + MSG_EPS;
        float nm = fmaxf(mx, v);
        float sc = __expf(mx - nm);
        float ex = __expf(v - nm);
        den = den * sc + ex;
        num = num * sc + ex * v;
        mx = nm;
    }
    float agg = (end > beg) ? num / den : 0.f;
    hin[(size_t)w * DD + lane] = agg + xdst[(size_t)w * DD + lane];
}

// ================= GEMM1: h1 = hin @ W1 + b1, accumulate BN stats ===============
__global__ __launch_bounds__(256) void gemm1_bn_k(
    const float* __restrict__ hin, const float* __restrict__ W1,
    const float* __restrict__ b1, float* __restrict__ h1,
    double* __restrict__ gsum, double* __restrict__ gsq, int N)
{
    __shared__ float sW[DD * DD2];          // 32 KB
    __shared__ float sx[32][DD + 1];
    __shared__ float sred[2][8][DD2];

    int t = threadIdx.x;
    for (int i = t; i < DD * DD2; i += 256) sW[i] = W1[i];
    int r0 = blockIdx.x * 32;
    for (int i = t; i < 32 * DD; i += 256) {
        int rr = i >> 6, k = i & 63, r = r0 + rr;
        sx[rr][k] = (r < N) ? hin[(size_t)r * DD + k] : 0.f;
    }
    __syncthreads();

    int tx = t & 31, ty = t >> 5;           // 32 col-groups x 8 row-groups
    float acc[4][4];
    #pragma unroll
    for (int i = 0; i < 4; i++)
        #pragma unroll
        for (int j = 0; j < 4; j++) acc[i][j] = 0.f;

    #pragma unroll 4
    for (int k = 0; k < DD; k++) {
        float4 w = ((const float4*)(sW + k * DD2))[tx];
        #pragma unroll
        for (int i = 0; i < 4; i++) {
            float xv = sx[ty * 4 + i][k];
            acc[i][0] = fmaf(xv, w.x, acc[i][0]);
            acc[i][1] = fmaf(xv, w.y, acc[i][1]);
            acc[i][2] = fmaf(xv, w.z, acc[i][2]);
            acc[i][3] = fmaf(xv, w.w, acc[i][3]);
        }
    }

    float4 bb = ((const float4*)b1)[tx];
    float ps[4] = {0,0,0,0}, pq[4] = {0,0,0,0};
    #pragma unroll
    for (int i = 0; i < 4; i++) {
        int r = r0 + ty * 4 + i;
        if (r < N) {
            float4 hv;
            hv.x = acc[i][0] + bb.x; hv.y = acc[i][1] + bb.y;
            hv.z = acc[i][2] + bb.z; hv.w = acc[i][3] + bb.w;
            ((float4*)(h1 + (size_t)r * DD2))[tx] = hv;
            ps[0] += hv.x; pq[0] += hv.x * hv.x;
            ps[1] += hv.y; pq[1] += hv.y * hv.y;
            ps[2] += hv.z; pq[2] += hv.z * hv.z;
            ps[3] += hv.w; pq[3] += hv.w * hv.w;
        }
    }
    #pragma unroll
    for (int j = 0; j < 4; j++) {
        sred[0][ty][tx * 4 + j] = ps[j];
        sred[1][ty][tx * 4 + j] = pq[j];
    }
    __syncthreads();
    if (t < DD2) {
        float s = 0.f, q = 0.f;
        #pragma unroll
        for (int y = 0; y < 8; y++) { s += sred[0][y][t]; q += sred[1][y][t]; }
        atomicAdd(&gsum[t], (double)s);
        atomicAdd(&gsq[t],  (double)q);
    }
}

// ================= BN finalize ====================================================
__global__ void bn_fin_k(const double* __restrict__ gsum, const double* __restrict__ gsq,
                         const float* __restrict__ gamma, const float* __restrict__ beta,
                         float2* __restrict__ ss, int N)
{
    int c = threadIdx.x;
    double mean = gsum[c] / (double)N;
    double var  = gsq[c] / (double)N - mean * mean;
    float inv = (float)(1.0 / sqrt(var + (double)BN_EPS));
    float sc = gamma[c] * inv;
    ss[c] = make_float2(sc, beta[c] - (float)mean * sc);
}

// ================= GEMM2: xnew = relu( relu(bn(h1)) @ W2 + b2 ) ==================
__global__ __launch_bounds__(256) void gemm2_k(
    const float* __restrict__ h1, const float2* __restrict__ ss,
    const float* __restrict__ W2, const float* __restrict__ b2,
    float* __restrict__ xnew, int N)
{
    __shared__ float sW[DD2 * DD];          // 32 KB
    __shared__ float sx[32][DD2 + 1];

    int t = threadIdx.x;
    for (int i = t; i < DD2 * DD; i += 256) sW[i] = W2[i];
    int r0 = blockIdx.x * 32;
    for (int i = t; i < 32 * DD2; i += 256) {
        int rr = i >> 7, k = i & 127, r = r0 + rr;
        float v = 0.f;
        if (r < N) {
            float2 sc = ss[k];
            v = fmaxf(fmaf(h1[(size_t)r * DD2 + k], sc.x, sc.y), 0.f);
        }
        sx[rr][k] = v;
    }
    __syncthreads();

    int tx = t & 15, ty = t >> 4;           // 16 col-groups x 16 row-groups
    float acc[2][4];
    #pragma unroll
    for (int i = 0; i < 2; i++)
        #pragma unroll
        for (int j = 0; j < 4; j++) acc[i][j] = 0.f;

    #pragma unroll 4
    for (int k = 0; k < DD2; k++) {
        float4 w = ((const float4*)(sW + k * DD))[tx];
        #pragma unroll
        for (int i = 0; i < 2; i++) {
            float xv = sx[ty * 2 + i][k];
            acc[i][0] = fmaf(xv, w.x, acc[i][0]);
            acc[i][1] = fmaf(xv, w.y, acc[i][1]);
            acc[i][2] = fmaf(xv, w.z, acc[i][2]);
            acc[i][3] = fmaf(xv, w.w, acc[i][3]);
        }
    }
    float4 bb = ((const float4*)b2)[tx];
    #pragma unroll
    for (int i = 0; i < 2; i++) {
        int r = r0 + ty * 2 + i;
        if (r < N) {
            float4 o;
            o.x = fmaxf(acc[i][0] + bb.x, 0.f);
            o.y = fmaxf(acc[i][1] + bb.y, 0.f);
            o.z = fmaxf(acc[i][2] + bb.z, 0.f);
            o.w = fmaxf(acc[i][3] + bb.w, 0.f);
            ((float4*)(xnew + (size_t)r * DD))[tx] = o;
        }
    }
}

// ================= decoder ========================================================
__global__ __launch_bounds__(256) void decode_k(
    const float* __restrict__ xu, const float* __restrict__ xi,
    const int* __restrict__ pu, const int* __restrict__ pi,
    float* __restrict__ out)
{
    int idx = blockIdx.x * 256 + threadIdx.x;
    int b = idx >> 4, lane = idx & 15;
    if (b >= NPRED) return;
    int u = pu[b], it = pi[b];
    float4 a = ((const float4*)(xu + (size_t)u * DD))[lane];
    float4 c = ((const float4*)(xi + (size_t)it * DD))[lane];
    float s = a.x * c.x + a.y * c.y + a.z * c.z + a.w * c.w;
    #pragma unroll
    for (int off = 8; off; off >>= 1) s += __shfl_down(s, off, 16);
    if (lane == 0) out[b] = s;
}

// ================= host-side conv driver ==========================================
static void run_conv(const float* xsrc, const float* xdst,
                     const int* rowptr, const int* csr, int Ndst,
                     const float* W1p, const float* b1p,
                     const float* gp, const float* bp,
                     const float* W2p, const float* b2p,
                     float* hin, float* h1, double* gsum, double* gsq,
                     float2* ss, float* xnew, hipStream_t stream)
{
    hipMemsetAsync(gsum, 0, 2 * DD2 * sizeof(double), stream); // gsum|gsq contiguous

    agg_k<<<(Ndst * 64 + 255) / 256, 256, 0, stream>>>(xsrc, xdst, rowptr, csr, hin, Ndst);

    int g1 = (Ndst + 31) / 32;
    gemm1_bn_k<<<g1, 256, 0, stream>>>(hin, W1p, b1p, h1, gsum, gsq, Ndst);
    bn_fin_k<<<1, DD2, 0, stream>>>(gsum, gsq, gp, bp, ss, Ndst);
    gemm2_k<<<g1, 256, 0, stream>>>(h1, ss, W2p, b2p, xnew, Ndst);
}

extern "C" void kernel_launch(void* const* d_in, const int* in_sizes, int n_in,
                              void* d_out, int out_size, void* d_ws, size_t ws_size,
                              hipStream_t stream)
{
    const float* x_user = (const float*)d_in[0];
    const float* x_item = (const float*)d_in[1];
    const float* W1    = (const float*)d_in[2];   // [3][2][64][128]
    const float* b1    = (const float*)d_in[3];
    const float* gamma = (const float*)d_in[4];
    const float* beta  = (const float*)d_in[5];
    const float* W2    = (const float*)d_in[6];   // [3][2][128][64]
    const float* b2    = (const float*)d_in[7];
    const int* edge = (const int*)d_in[8];        // [2][E]
    const int* pred = (const int*)d_in[9];        // [2][B]
    float* out = (float*)d_out;

    const int* u_idx = edge;
    const int* i_idx = edge + NEDG;

    // ---- workspace bump allocator (256B aligned chunks) ----
    char* p = (char*)d_ws;
    #define ALLOC(ptr, type, count) \
        type* ptr = (type*)p; p += (((size_t)(count) * sizeof(type)) + 255) & ~(size_t)255;

    ALLOC(deg_i, int, NITM)
    ALLOC(deg_u, int, NUSR)          // deg_i|deg_u contiguous-ish; memset separately
    ALLOC(part_i, int, NITM)
    ALLOC(part_u, int, NUSR)
    ALLOC(bsum_i, int, 128)
    ALLOC(bsum_u, int, 128)
    ALLOC(rowptr_i, int, NITM + 1)
    ALLOC(rowptr_u, int, NUSR + 1)
    ALLOC(cur_i, int, NITM)
    ALLOC(cur_u, int, NUSR)
    ALLOC(csr_i, int, NEDG)          // per-item incident users
    ALLOC(csr_u, int, NEDG)          // per-user incident items
    ALLOC(hin, float, (size_t)NUSR * DD)
    ALLOC(h1, float, (size_t)NUSR * DD2)
    ALLOC(gsum, double, DD2)
    ALLOC(gsq, double, DD2)
    ALLOC(ss, float2, DD2)
    ALLOC(xu0, float, (size_t)NUSR * DD)
    ALLOC(xu1, float, (size_t)NUSR * DD)
    ALLOC(xi0, float, (size_t)NITM * DD)
    ALLOC(xi1, float, (size_t)NITM * DD)
    #undef ALLOC
    float* xu_buf[2] = {xu0, xu1};
    float* xi_buf[2] = {xi0, xi1};

    // ---- CSR build (once; reused by all 3 layers) ----
    hipMemsetAsync(deg_i, 0, NITM * sizeof(int), stream);
    hipMemsetAsync(deg_u, 0, NUSR * sizeof(int), stream);
    count_k<<<(NEDG + 255) / 256, 256, 0, stream>>>(u_idx, i_idx, deg_u, deg_i);

    int nbi = (NITM + SCAN_B - 1) / SCAN_B;   // 49
    int nbu = (NUSR + SCAN_B - 1) / SCAN_B;   // 98
    scan1_k<<<nbi, SCAN_B, 0, stream>>>(deg_i, part_i, bsum_i, NITM);
    scan2_k<<<1, 128, 0, stream>>>(bsum_i, nbi);
    scan3_k<<<nbi, SCAN_B, 0, stream>>>(deg_i, part_i, bsum_i, rowptr_i, cur_i, NITM);
    scan1_k<<<nbu, SCAN_B, 0, stream>>>(deg_u, part_u, bsum_u, NUSR);
    scan2_k<<<1, 128, 0, stream>>>(bsum_u, nbu);
    scan3_k<<<nbu, SCAN_B, 0, stream>>>(deg_u, part_u, bsum_u, rowptr_u, cur_u, NUSR);
    scatter_k<<<(NEDG + 255) / 256, 256, 0, stream>>>(u_idx, i_idx, cur_i, cur_u, csr_i, csr_u);

    // ---- 3 layers x 2 convs ----
    const float* cu = x_user;
    const float* ci = x_item;
    for (int l = 0; l < 3; l++) {
        size_t o0 = (size_t)l * 2 + 0;   // user->item conv params
        size_t o1 = (size_t)l * 2 + 1;   // item->user conv params
        float* ni = xi_buf[l & 1];
        float* nu = xu_buf[l & 1];
        run_conv(cu, ci, rowptr_i, csr_i, NITM,
                 W1 + o0 * DD * DD2, b1 + o0 * DD2, gamma + o0 * DD2, beta + o0 * DD2,
                 W2 + o0 * DD2 * DD, b2 + o0 * DD,
                 hin, h1, gsum, gsq, ss, ni, stream);
        run_conv(ci, cu, rowptr_u, csr_u, NUSR,
                 W1 + o1 * DD * DD2, b1 + o1 * DD2, gamma + o1 * DD2, beta + o1 * DD2,
                 W2 + o1 * DD2 * DD, b2 + o1 * DD,
                 hin, h1, gsum, gsq, ss, nu, stream);
        cu = nu; ci = ni;
    }

    decode_k<<<(NPRED * 16) / 256, 256, 0, stream>>>(cu, ci, pred, pred + NPRED, out);
}

// Round 3
// 1356.758 us; speedup vs baseline: 3.2751x; 1.2472x over previous
//
#include <hip/hip_runtime.h>

#define NUSR 100000
#define NITM 50000
#define NEDG 1000000
#define NPRED 250000
#define DD 64
#define DD2 128
#define MSG_EPS 1e-7f
#define BN_EPS 1e-5f
#define SCAN_B 1024

// ================= CSR build (once per call; edges are layer-invariant) ==========

__global__ __launch_bounds__(256) void count_k(
    const int* __restrict__ u_idx, const int* __restrict__ i_idx,
    int* __restrict__ deg_u, int* __restrict__ deg_i)
{
    int e = blockIdx.x * 256 + threadIdx.x;
    if (e >= NEDG) return;
    atomicAdd(&deg_i[i_idx[e]], 1);
    atomicAdd(&deg_u[u_idx[e]], 1);
}

// inclusive scan per 1024-chunk; block totals to bsum
__global__ __launch_bounds__(SCAN_B) void scan1_k(
    const int* __restrict__ deg, int* __restrict__ partial, int* __restrict__ bsum, int n)
{
    __shared__ int s[SCAN_B];
    int tid = threadIdx.x;
    int i = blockIdx.x * SCAN_B + tid;
    s[tid] = (i < n) ? deg[i] : 0;
    __syncthreads();
    for (int off = 1; off < SCAN_B; off <<= 1) {
        int t = (tid >= off) ? s[tid - off] : 0;
        __syncthreads();
        s[tid] += t;
        __syncthreads();
    }
    if (i < n) partial[i] = s[tid];
    if (tid == SCAN_B - 1) bsum[blockIdx.x] = s[tid];
}

// exclusive scan of block sums (nb <= 128), single block
__global__ __launch_bounds__(128) void scan2_k(int* __restrict__ bsum, int nb)
{
    __shared__ int s[128];
    int tid = threadIdx.x;
    s[tid] = (tid < nb) ? bsum[tid] : 0;
    __syncthreads();
    for (int off = 1; off < 128; off <<= 1) {
        int t = (tid >= off) ? s[tid - off] : 0;
        __syncthreads();
        s[tid] += t;
        __syncthreads();
    }
    if (tid < nb) bsum[tid] = (tid == 0) ? 0 : s[tid - 1];
}

// rowptr (exclusive) + cursor init; rowptr[n] = E
__global__ __launch_bounds__(SCAN_B) void scan3_k(
    const int* __restrict__ deg, const int* __restrict__ partial,
    const int* __restrict__ bsum, int* __restrict__ rowptr, int* __restrict__ cursor, int n)
{
    int i = blockIdx.x * SCAN_B + threadIdx.x;
    if (i < n) {
        int rs = partial[i] - deg[i] + bsum[blockIdx.x];
        rowptr[i] = rs;
        cursor[i] = rs;
    }
    if (i == 0) rowptr[n] = NEDG;
}

__global__ __launch_bounds__(256) void scatter_k(
    const int* __restrict__ u_idx, const int* __restrict__ i_idx,
    int* __restrict__ cur_i, int* __restrict__ cur_u,
    int* __restrict__ csr_i, int* __restrict__ csr_u)
{
    int e = blockIdx.x * 256 + threadIdx.x;
    if (e >= NEDG) return;
    int u = u_idx[e], it = i_idx[e];
    int p = atomicAdd(&cur_i[it], 1); csr_i[p] = u;   // item's incident users
    int q = atomicAdd(&cur_u[u], 1);  csr_u[q] = it;  // user's incident items
}

// ================= aggregation: one wave per dst row, online softmax =============
// 4-way unrolled: 4 independent gathers in flight per wave (latency hiding).
__global__ __launch_bounds__(256) void agg_k(
    const float* __restrict__ xsrc, const float* __restrict__ xdst,
    const int* __restrict__ rowptr, const int* __restrict__ csr,
    float* __restrict__ hin, int N)
{
    int idx = blockIdx.x * 256 + threadIdx.x;
    int w = idx >> 6, lane = idx & 63;
    if (w >= N) return;
    int beg = rowptr[w], end = rowptr[w + 1];
    float mx = -1e30f, den = 0.f, num = 0.f;

    int j = beg;
    for (; j + 4 <= end; j += 4) {
        int s0 = csr[j], s1 = csr[j + 1], s2 = csr[j + 2], s3 = csr[j + 3];
        float v0 = xsrc[(size_t)s0 * DD + lane];
        float v1 = xsrc[(size_t)s1 * DD + lane];
        float v2 = xsrc[(size_t)s2 * DD + lane];
        float v3 = xsrc[(size_t)s3 * DD + lane];
        v0 = fmaxf(v0, 0.f) + MSG_EPS;
        v1 = fmaxf(v1, 0.f) + MSG_EPS;
        v2 = fmaxf(v2, 0.f) + MSG_EPS;
        v3 = fmaxf(v3, 0.f) + MSG_EPS;
        #pragma unroll
        for (int q = 0; q < 4; q++) {
            float v = (q == 0) ? v0 : (q == 1) ? v1 : (q == 2) ? v2 : v3;
            float nm = fmaxf(mx, v);
            float sc = __expf(mx - nm);
            float ex = __expf(v - nm);
            den = den * sc + ex;
            num = num * sc + ex * v;
            mx = nm;
        }
    }
    for (; j < end; j++) {
        int s = csr[j];
        float v = fmaxf(xsrc[(size_t)s * DD + lane], 0.f) + MSG_EPS;
        float nm = fmaxf(mx, v);
        float sc = __expf(mx - nm);
        float ex = __expf(v - nm);
        den = den * sc + ex;
        num = num * sc + ex * v;
        mx = nm;
    }
    float agg = (end > beg) ? num / den : 0.f;
    hin[(size_t)w * DD + lane] = agg + xdst[(size_t)w * DD + lane];
}

// ================= GEMM1: h1 = hin @ W1 + b1, accumulate BN stats ===============
__global__ __launch_bounds__(256) void gemm1_bn_k(
    const float* __restrict__ hin, const float* __restrict__ W1,
    const float* __restrict__ b1, float* __restrict__ h1,
    double* __restrict__ gsum, double* __restrict__ gsq, int N)
{
    __shared__ float sW[DD * DD2];          // 32 KB
    __shared__ float sx[32][DD + 1];
    __shared__ float sred[2][8][DD2];

    int t = threadIdx.x;
    for (int i = t; i < DD * DD2; i += 256) sW[i] = W1[i];
    int r0 = blockIdx.x * 32;
    for (int i = t; i < 32 * DD; i += 256) {
        int rr = i >> 6, k = i & 63, r = r0 + rr;
        sx[rr][k] = (r < N) ? hin[(size_t)r * DD + k] : 0.f;
    }
    __syncthreads();

    int tx = t & 31, ty = t >> 5;           // 32 col-groups x 8 row-groups
    float acc[4][4];
    #pragma unroll
    for (int i = 0; i < 4; i++)
        #pragma unroll
        for (int j = 0; j < 4; j++) acc[i][j] = 0.f;

    #pragma unroll 4
    for (int k = 0; k < DD; k++) {
        float4 w = ((const float4*)(sW + k * DD2))[tx];
        #pragma unroll
        for (int i = 0; i < 4; i++) {
            float xv = sx[ty * 4 + i][k];
            acc[i][0] = fmaf(xv, w.x, acc[i][0]);
            acc[i][1] = fmaf(xv, w.y, acc[i][1]);
            acc[i][2] = fmaf(xv, w.z, acc[i][2]);
            acc[i][3] = fmaf(xv, w.w, acc[i][3]);
        }
    }

    float4 bb = ((const float4*)b1)[tx];
    float ps[4] = {0,0,0,0}, pq[4] = {0,0,0,0};
    #pragma unroll
    for (int i = 0; i < 4; i++) {
        int r = r0 + ty * 4 + i;
        if (r < N) {
            float4 hv;
            hv.x = acc[i][0] + bb.x; hv.y = acc[i][1] + bb.y;
            hv.z = acc[i][2] + bb.z; hv.w = acc[i][3] + bb.w;
            ((float4*)(h1 + (size_t)r * DD2))[tx] = hv;
            ps[0] += hv.x; pq[0] += hv.x * hv.x;
            ps[1] += hv.y; pq[1] += hv.y * hv.y;
            ps[2] += hv.z; pq[2] += hv.z * hv.z;
            ps[3] += hv.w; pq[3] += hv.w * hv.w;
        }
    }
    #pragma unroll
    for (int j = 0; j < 4; j++) {
        sred[0][ty][tx * 4 + j] = ps[j];
        sred[1][ty][tx * 4 + j] = pq[j];
    }
    __syncthreads();
    if (t < DD2) {
        float s = 0.f, q = 0.f;
        #pragma unroll
        for (int y = 0; y < 8; y++) { s += sred[0][y][t]; q += sred[1][y][t]; }
        atomicAdd(&gsum[t], (double)s);
        atomicAdd(&gsq[t],  (double)q);
    }
}

// ===== GEMM2: xnew = relu( relu(bn(h1)) @ W2 + b2 ); BN scale/shift in prologue ==
__global__ __launch_bounds__(256) void gemm2_k(
    const float* __restrict__ h1,
    const double* __restrict__ gsum, const double* __restrict__ gsq,
    const float* __restrict__ gamma, const float* __restrict__ beta,
    const float* __restrict__ W2, const float* __restrict__ b2,
    float* __restrict__ xnew, int N)
{
    __shared__ float sW[DD2 * DD];          // 32 KB
    __shared__ float sx[32][DD2 + 1];
    __shared__ float2 sss[DD2];

    int t = threadIdx.x;
    if (t < DD2) {
        double mean = gsum[t] / (double)N;
        double var  = gsq[t] / (double)N - mean * mean;
        float inv = (float)(1.0 / sqrt(var + (double)BN_EPS));
        float sc = gamma[t] * inv;
        sss[t] = make_float2(sc, beta[t] - (float)mean * sc);
    }
    for (int i = t; i < DD2 * DD; i += 256) sW[i] = W2[i];
    __syncthreads();

    int r0 = blockIdx.x * 32;
    for (int i = t; i < 32 * DD2; i += 256) {
        int rr = i >> 7, k = i & 127, r = r0 + rr;
        float v = 0.f;
        if (r < N) {
            float2 sc = sss[k];
            v = fmaxf(fmaf(h1[(size_t)r * DD2 + k], sc.x, sc.y), 0.f);
        }
        sx[rr][k] = v;
    }
    __syncthreads();

    int tx = t & 15, ty = t >> 4;           // 16 col-groups x 16 row-groups
    float acc[2][4];
    #pragma unroll
    for (int i = 0; i < 2; i++)
        #pragma unroll
        for (int j = 0; j < 4; j++) acc[i][j] = 0.f;

    #pragma unroll 4
    for (int k = 0; k < DD2; k++) {
        float4 w = ((const float4*)(sW + k * DD))[tx];
        #pragma unroll
        for (int i = 0; i < 2; i++) {
            float xv = sx[ty * 2 + i][k];
            acc[i][0] = fmaf(xv, w.x, acc[i][0]);
            acc[i][1] = fmaf(xv, w.y, acc[i][1]);
            acc[i][2] = fmaf(xv, w.z, acc[i][2]);
            acc[i][3] = fmaf(xv, w.w, acc[i][3]);
        }
    }
    float4 bb = ((const float4*)b2)[tx];
    #pragma unroll
    for (int i = 0; i < 2; i++) {
        int r = r0 + ty * 2 + i;
        if (r < N) {
            float4 o;
            o.x = fmaxf(acc[i][0] + bb.x, 0.f);
            o.y = fmaxf(acc[i][1] + bb.y, 0.f);
            o.z = fmaxf(acc[i][2] + bb.z, 0.f);
            o.w = fmaxf(acc[i][3] + bb.w, 0.f);
            ((float4*)(xnew + (size_t)r * DD))[tx] = o;
        }
    }
}

// ================= decoder ========================================================
__global__ __launch_bounds__(256) void decode_k(
    const float* __restrict__ xu, const float* __restrict__ xi,
    const int* __restrict__ pu, const int* __restrict__ pi,
    float* __restrict__ out)
{
    int idx = blockIdx.x * 256 + threadIdx.x;
    int b = idx >> 4, lane = idx & 15;
    if (b >= NPRED) return;
    int u = pu[b], it = pi[b];
    float4 a = ((const float4*)(xu + (size_t)u * DD))[lane];
    float4 c = ((const float4*)(xi + (size_t)it * DD))[lane];
    float s = a.x * c.x + a.y * c.y + a.z * c.z + a.w * c.w;
    #pragma unroll
    for (int off = 8; off; off >>= 1) s += __shfl_down(s, off, 16);
    if (lane == 0) out[b] = s;
}

// ================= host-side conv driver ==========================================
static void run_conv(const float* xsrc, const float* xdst,
                     const int* rowptr, const int* csr, int Ndst,
                     const float* W1p, const float* b1p,
                     const float* gp, const float* bp,
                     const float* W2p, const float* b2p,
                     float* hin, float* h1, double* gsum, double* gsq,
                     float* xnew, hipStream_t stream)
{
    hipMemsetAsync(gsum, 0, 2 * DD2 * sizeof(double), stream); // gsum|gsq contiguous

    agg_k<<<(Ndst * 64 + 255) / 256, 256, 0, stream>>>(xsrc, xdst, rowptr, csr, hin, Ndst);

    int g1 = (Ndst + 31) / 32;
    gemm1_bn_k<<<g1, 256, 0, stream>>>(hin, W1p, b1p, h1, gsum, gsq, Ndst);
    gemm2_k<<<g1, 256, 0, stream>>>(h1, gsum, gsq, gp, bp, W2p, b2p, xnew, Ndst);
}

extern "C" void kernel_launch(void* const* d_in, const int* in_sizes, int n_in,
                              void* d_out, int out_size, void* d_ws, size_t ws_size,
                              hipStream_t stream)
{
    const float* x_user = (const float*)d_in[0];
    const float* x_item = (const float*)d_in[1];
    const float* W1    = (const float*)d_in[2];   // [3][2][64][128]
    const float* b1    = (const float*)d_in[3];
    const float* gamma = (const float*)d_in[4];
    const float* beta  = (const float*)d_in[5];
    const float* W2    = (const float*)d_in[6];   // [3][2][128][64]
    const float* b2    = (const float*)d_in[7];
    const int* edge = (const int*)d_in[8];        // [2][E]
    const int* pred = (const int*)d_in[9];        // [2][B]
    float* out = (float*)d_out;

    const int* u_idx = edge;
    const int* i_idx = edge + NEDG;

    // ---- workspace bump allocator (256B aligned chunks) ----
    char* p = (char*)d_ws;
    #define ALLOC(ptr, type, count) \
        type* ptr = (type*)p; p += (((size_t)(count) * sizeof(type)) + 255) & ~(size_t)255;

    ALLOC(deg_i, int, NITM)
    ALLOC(deg_u, int, NUSR)
    ALLOC(part_i, int, NITM)
    ALLOC(part_u, int, NUSR)
    ALLOC(bsum_i, int, 128)
    ALLOC(bsum_u, int, 128)
    ALLOC(rowptr_i, int, NITM + 1)
    ALLOC(rowptr_u, int, NUSR + 1)
    ALLOC(cur_i, int, NITM)
    ALLOC(cur_u, int, NUSR)
    ALLOC(csr_i, int, NEDG)          // per-item incident users
    ALLOC(csr_u, int, NEDG)          // per-user incident items
    ALLOC(hin, float, (size_t)NUSR * DD)
    ALLOC(h1, float, (size_t)NUSR * DD2)
    ALLOC(gsum, double, DD2)
    ALLOC(gsq, double, DD2)
    ALLOC(xu0, float, (size_t)NUSR * DD)
    ALLOC(xu1, float, (size_t)NUSR * DD)
    ALLOC(xi0, float, (size_t)NITM * DD)
    ALLOC(xi1, float, (size_t)NITM * DD)
    #undef ALLOC
    float* xu_buf[2] = {xu0, xu1};
    float* xi_buf[2] = {xi0, xi1};

    // ---- CSR build (once; reused by all 3 layers) ----
    hipMemsetAsync(deg_i, 0, NITM * sizeof(int), stream);
    hipMemsetAsync(deg_u, 0, NUSR * sizeof(int), stream);
    count_k<<<(NEDG + 255) / 256, 256, 0, stream>>>(u_idx, i_idx, deg_u, deg_i);

    int nbi = (NITM + SCAN_B - 1) / SCAN_B;   // 49
    int nbu = (NUSR + SCAN_B - 1) / SCAN_B;   // 98
    scan1_k<<<nbi, SCAN_B, 0, stream>>>(deg_i, part_i, bsum_i, NITM);
    scan2_k<<<1, 128, 0, stream>>>(bsum_i, nbi);
    scan3_k<<<nbi, SCAN_B, 0, stream>>>(deg_i, part_i, bsum_i, rowptr_i, cur_i, NITM);
    scan1_k<<<nbu, SCAN_B, 0, stream>>>(deg_u, part_u, bsum_u, NUSR);
    scan2_k<<<1, 128, 0, stream>>>(bsum_u, nbu);
    scan3_k<<<nbu, SCAN_B, 0, stream>>>(deg_u, part_u, bsum_u, rowptr_u, cur_u, NUSR);
    scatter_k<<<(NEDG + 255) / 256, 256, 0, stream>>>(u_idx, i_idx, cur_i, cur_u, csr_i, csr_u);

    // ---- 3 layers x 2 convs ----
    const float* cu = x_user;
    const float* ci = x_item;
    for (int l = 0; l < 3; l++) {
        size_t o0 = (size_t)l * 2 + 0;   // user->item conv params
        size_t o1 = (size_t)l * 2 + 1;   // item->user conv params
        float* ni = xi_buf[l & 1];
        float* nu = xu_buf[l & 1];
        run_conv(cu, ci, rowptr_i, csr_i, NITM,
                 W1 + o0 * DD * DD2, b1 + o0 * DD2, gamma + o0 * DD2, beta + o0 * DD2,
                 W2 + o0 * DD2 * DD, b2 + o0 * DD,
                 hin, h1, gsum, gsq, ni, stream);
        run_conv(ci, cu, rowptr_u, csr_u, NUSR,
                 W1 + o1 * DD * DD2, b1 + o1 * DD2, gamma + o1 * DD2, beta + o1 * DD2,
                 W2 + o1 * DD2 * DD, b2 + o1 * DD,
                 hin, h1, gsum, gsq, nu, stream);
        cu = nu; ci = ni;
    }

    decode_k<<<(NPRED * 16) / 256, 256, 0, stream>>>(cu, ci, pred, pred + NPRED, out);
}

// Round 4
// 1292.744 us; speedup vs baseline: 3.4373x; 1.0495x over previous
//
#include <hip/hip_runtime.h>
#include <hip/hip_fp16.h>

#define NUSR 100000
#define NITM 50000
#define NEDG 1000000
#define NPRED 250000
#define DD 64
#define DD2 128
#define MSG_EPS 1e-7f
#define BN_EPS 1e-5f
#define SCAN_B 1024

// ================= CSR build (once per call; edges are layer-invariant) ==========

__global__ __launch_bounds__(256) void count_k(
    const int* __restrict__ u_idx, const int* __restrict__ i_idx,
    int* __restrict__ deg_u, int* __restrict__ deg_i)
{
    int e = blockIdx.x * 256 + threadIdx.x;
    if (e >= NEDG) return;
    atomicAdd(&deg_i[i_idx[e]], 1);
    atomicAdd(&deg_u[u_idx[e]], 1);
}

__global__ __launch_bounds__(SCAN_B) void scan1_k(
    const int* __restrict__ deg, int* __restrict__ partial, int* __restrict__ bsum, int n)
{
    __shared__ int s[SCAN_B];
    int tid = threadIdx.x;
    int i = blockIdx.x * SCAN_B + tid;
    s[tid] = (i < n) ? deg[i] : 0;
    __syncthreads();
    for (int off = 1; off < SCAN_B; off <<= 1) {
        int t = (tid >= off) ? s[tid - off] : 0;
        __syncthreads();
        s[tid] += t;
        __syncthreads();
    }
    if (i < n) partial[i] = s[tid];
    if (tid == SCAN_B - 1) bsum[blockIdx.x] = s[tid];
}

__global__ __launch_bounds__(128) void scan2_k(int* __restrict__ bsum, int nb)
{
    __shared__ int s[128];
    int tid = threadIdx.x;
    s[tid] = (tid < nb) ? bsum[tid] : 0;
    __syncthreads();
    for (int off = 1; off < 128; off <<= 1) {
        int t = (tid >= off) ? s[tid - off] : 0;
        __syncthreads();
        s[tid] += t;
        __syncthreads();
    }
    if (tid < nb) bsum[tid] = (tid == 0) ? 0 : s[tid - 1];
}

__global__ __launch_bounds__(SCAN_B) void scan3_k(
    const int* __restrict__ deg, const int* __restrict__ partial,
    const int* __restrict__ bsum, int* __restrict__ rowptr, int* __restrict__ cursor, int n)
{
    int i = blockIdx.x * SCAN_B + threadIdx.x;
    if (i < n) {
        int rs = partial[i] - deg[i] + bsum[blockIdx.x];
        rowptr[i] = rs;
        cursor[i] = rs;
    }
    if (i == 0) rowptr[n] = NEDG;
}

__global__ __launch_bounds__(256) void scatter_k(
    const int* __restrict__ u_idx, const int* __restrict__ i_idx,
    int* __restrict__ cur_i, int* __restrict__ cur_u,
    int* __restrict__ csr_i, int* __restrict__ csr_u)
{
    int e = blockIdx.x * 256 + threadIdx.x;
    if (e >= NEDG) return;
    int u = u_idx[e], it = i_idx[e];
    int p = atomicAdd(&cur_i[it], 1); csr_i[p] = u;   // item's incident users
    int q = atomicAdd(&cur_u[u], 1);  csr_u[q] = it;  // user's incident items
}

// ========== layer-0 message precompute: msg = half(relu(x)+eps) ==================
__global__ __launch_bounds__(256) void msg0_k(
    const float* __restrict__ x, __half* __restrict__ msg, int n4)
{
    int i = blockIdx.x * 256 + threadIdx.x;
    if (i >= n4) return;
    float4 v = ((const float4*)x)[i];
    __half2 a = __floats2half2_rn(fmaxf(v.x, 0.f) + MSG_EPS, fmaxf(v.y, 0.f) + MSG_EPS);
    __half2 b = __floats2half2_rn(fmaxf(v.z, 0.f) + MSG_EPS, fmaxf(v.w, 0.f) + MSG_EPS);
    ((__half2*)msg)[i * 2]     = a;
    ((__half2*)msg)[i * 2 + 1] = b;
}

// ============ aggregation: 2 rows/wave (32 lanes x half2 each), online softmax ===
#define OS_UPDATE(vx, vy)                                                   \
    {                                                                       \
        float nm0 = fmaxf(mx0, vx);                                         \
        float sc0 = __expf(mx0 - nm0), e0 = __expf(vx - nm0);               \
        d0 = d0 * sc0 + e0; n0 = n0 * sc0 + e0 * (vx); mx0 = nm0;           \
        float nm1 = fmaxf(mx1, vy);                                         \
        float sc1 = __expf(mx1 - nm1), e1 = __expf(vy - nm1);               \
        d1 = d1 * sc1 + e1; n1 = n1 * sc1 + e1 * (vy); mx1 = nm1;           \
    }

__global__ __launch_bounds__(256) void agg_k(
    const __half* __restrict__ msg, const float* __restrict__ xdst,
    const int* __restrict__ rowptr, const int* __restrict__ csr,
    float* __restrict__ hin, int N)
{
    int idx = blockIdx.x * 256 + threadIdx.x;
    int wid = idx >> 6;
    int lane = threadIdx.x & 63;
    int r = wid * 2 + (lane >> 5);      // 2 rows per wave
    int fp = lane & 31;                 // feature-pair index (half2 / float2)
    if (r >= N) return;
    int beg = rowptr[r], end = rowptr[r + 1];
    const __half2* mp = (const __half2*)msg;

    float mx0 = -1e30f, mx1 = -1e30f, d0 = 0.f, d1 = 0.f, n0 = 0.f, n1 = 0.f;
    int j = beg;
    for (; j + 4 <= end; j += 4) {
        int s0 = csr[j], s1 = csr[j + 1], s2 = csr[j + 2], s3 = csr[j + 3];
        __half2 h0 = mp[(size_t)s0 * 32 + fp];
        __half2 h1 = mp[(size_t)s1 * 32 + fp];
        __half2 h2 = mp[(size_t)s2 * 32 + fp];
        __half2 h3 = mp[(size_t)s3 * 32 + fp];
        float2 v0 = __half22float2(h0);
        float2 v1 = __half22float2(h1);
        float2 v2 = __half22float2(h2);
        float2 v3 = __half22float2(h3);
        OS_UPDATE(v0.x, v0.y)
        OS_UPDATE(v1.x, v1.y)
        OS_UPDATE(v2.x, v2.y)
        OS_UPDATE(v3.x, v3.y)
    }
    for (; j < end; j++) {
        float2 v = __half22float2(mp[(size_t)csr[j] * 32 + fp]);
        OS_UPDATE(v.x, v.y)
    }
    float ax = (end > beg) ? n0 / d0 : 0.f;
    float ay = (end > beg) ? n1 / d1 : 0.f;
    float2 xd = ((const float2*)xdst)[(size_t)r * 32 + fp];
    float2 o; o.x = ax + xd.x; o.y = ay + xd.y;
    ((float2*)hin)[(size_t)r * 32 + fp] = o;
}

// ================= GEMM1: h1 = hin @ W1 + b1, accumulate BN stats ===============
__global__ __launch_bounds__(256) void gemm1_bn_k(
    const float* __restrict__ hin, const float* __restrict__ W1,
    const float* __restrict__ b1, float* __restrict__ h1,
    double* __restrict__ gsum, double* __restrict__ gsq, int N)
{
    __shared__ float sW[DD * DD2];          // 32 KB
    __shared__ float sx[32][DD + 1];
    __shared__ float sred[2][8][DD2];

    int t = threadIdx.x;
    for (int i = t; i < DD * DD2; i += 256) sW[i] = W1[i];
    int r0 = blockIdx.x * 32;
    for (int i = t; i < 32 * DD; i += 256) {
        int rr = i >> 6, k = i & 63, r = r0 + rr;
        sx[rr][k] = (r < N) ? hin[(size_t)r * DD + k] : 0.f;
    }
    __syncthreads();

    int tx = t & 31, ty = t >> 5;           // 32 col-groups x 8 row-groups
    float acc[4][4];
    #pragma unroll
    for (int i = 0; i < 4; i++)
        #pragma unroll
        for (int j = 0; j < 4; j++) acc[i][j] = 0.f;

    #pragma unroll 4
    for (int k = 0; k < DD; k++) {
        float4 w = ((const float4*)(sW + k * DD2))[tx];
        #pragma unroll
        for (int i = 0; i < 4; i++) {
            float xv = sx[ty * 4 + i][k];
            acc[i][0] = fmaf(xv, w.x, acc[i][0]);
            acc[i][1] = fmaf(xv, w.y, acc[i][1]);
            acc[i][2] = fmaf(xv, w.z, acc[i][2]);
            acc[i][3] = fmaf(xv, w.w, acc[i][3]);
        }
    }

    float4 bb = ((const float4*)b1)[tx];
    float ps[4] = {0,0,0,0}, pq[4] = {0,0,0,0};
    #pragma unroll
    for (int i = 0; i < 4; i++) {
        int r = r0 + ty * 4 + i;
        if (r < N) {
            float4 hv;
            hv.x = acc[i][0] + bb.x; hv.y = acc[i][1] + bb.y;
            hv.z = acc[i][2] + bb.z; hv.w = acc[i][3] + bb.w;
            ((float4*)(h1 + (size_t)r * DD2))[tx] = hv;
            ps[0] += hv.x; pq[0] += hv.x * hv.x;
            ps[1] += hv.y; pq[1] += hv.y * hv.y;
            ps[2] += hv.z; pq[2] += hv.z * hv.z;
            ps[3] += hv.w; pq[3] += hv.w * hv.w;
        }
    }
    #pragma unroll
    for (int j = 0; j < 4; j++) {
        sred[0][ty][tx * 4 + j] = ps[j];
        sred[1][ty][tx * 4 + j] = pq[j];
    }
    __syncthreads();
    if (t < DD2) {
        float s = 0.f, q = 0.f;
        #pragma unroll
        for (int y = 0; y < 8; y++) { s += sred[0][y][t]; q += sred[1][y][t]; }
        atomicAdd(&gsum[t], (double)s);
        atomicAdd(&gsq[t],  (double)q);
    }
}

// ===== GEMM2: xnew = relu( relu(bn(h1)) @ W2 + b2 ), + msg epilogue ==============
__global__ __launch_bounds__(256) void gemm2_k(
    const float* __restrict__ h1,
    const double* __restrict__ gsum, const double* __restrict__ gsq,
    const float* __restrict__ gamma, const float* __restrict__ beta,
    const float* __restrict__ W2, const float* __restrict__ b2,
    float* __restrict__ xnew, __half* __restrict__ msgout, int N)
{
    __shared__ float sW[DD2 * DD];          // 32 KB
    __shared__ float sx[32][DD2 + 1];
    __shared__ float2 sss[DD2];

    int t = threadIdx.x;
    if (t < DD2) {
        double mean = gsum[t] / (double)N;
        double var  = gsq[t] / (double)N - mean * mean;
        float inv = (float)(1.0 / sqrt(var + (double)BN_EPS));
        float sc = gamma[t] * inv;
        sss[t] = make_float2(sc, beta[t] - (float)mean * sc);
    }
    for (int i = t; i < DD2 * DD; i += 256) sW[i] = W2[i];
    __syncthreads();

    int r0 = blockIdx.x * 32;
    for (int i = t; i < 32 * DD2; i += 256) {
        int rr = i >> 7, k = i & 127, r = r0 + rr;
        float v = 0.f;
        if (r < N) {
            float2 sc = sss[k];
            v = fmaxf(fmaf(h1[(size_t)r * DD2 + k], sc.x, sc.y), 0.f);
        }
        sx[rr][k] = v;
    }
    __syncthreads();

    int tx = t & 15, ty = t >> 4;           // 16 col-groups x 16 row-groups
    float acc[2][4];
    #pragma unroll
    for (int i = 0; i < 2; i++)
        #pragma unroll
        for (int j = 0; j < 4; j++) acc[i][j] = 0.f;

    #pragma unroll 4
    for (int k = 0; k < DD2; k++) {
        float4 w = ((const float4*)(sW + k * DD))[tx];
        #pragma unroll
        for (int i = 0; i < 2; i++) {
            float xv = sx[ty * 2 + i][k];
            acc[i][0] = fmaf(xv, w.x, acc[i][0]);
            acc[i][1] = fmaf(xv, w.y, acc[i][1]);
            acc[i][2] = fmaf(xv, w.z, acc[i][2]);
            acc[i][3] = fmaf(xv, w.w, acc[i][3]);
        }
    }
    float4 bb = ((const float4*)b2)[tx];
    #pragma unroll
    for (int i = 0; i < 2; i++) {
        int r = r0 + ty * 2 + i;
        if (r < N) {
            float4 o;
            o.x = fmaxf(acc[i][0] + bb.x, 0.f);
            o.y = fmaxf(acc[i][1] + bb.y, 0.f);
            o.z = fmaxf(acc[i][2] + bb.z, 0.f);
            o.w = fmaxf(acc[i][3] + bb.w, 0.f);
            ((float4*)(xnew + (size_t)r * DD))[tx] = o;
            // msg for next conv that gathers from this side: half(out + eps)
            __half2 ha = __floats2half2_rn(o.x + MSG_EPS, o.y + MSG_EPS);
            __half2 hb = __floats2half2_rn(o.z + MSG_EPS, o.w + MSG_EPS);
            ((__half2*)msgout)[(size_t)r * 32 + tx * 2]     = ha;
            ((__half2*)msgout)[(size_t)r * 32 + tx * 2 + 1] = hb;
        }
    }
}

// ================= decoder ========================================================
__global__ __launch_bounds__(256) void decode_k(
    const float* __restrict__ xu, const float* __restrict__ xi,
    const int* __restrict__ pu, const int* __restrict__ pi,
    float* __restrict__ out)
{
    int idx = blockIdx.x * 256 + threadIdx.x;
    int b = idx >> 4, lane = idx & 15;
    if (b >= NPRED) return;
    int u = pu[b], it = pi[b];
    float4 a = ((const float4*)(xu + (size_t)u * DD))[lane];
    float4 c = ((const float4*)(xi + (size_t)it * DD))[lane];
    float s = a.x * c.x + a.y * c.y + a.z * c.z + a.w * c.w;
    #pragma unroll
    for (int off = 8; off; off >>= 1) s += __shfl_down(s, off, 16);
    if (lane == 0) out[b] = s;
}

// ================= host-side conv driver ==========================================
static void run_conv(const __half* msg_src, const float* xdst,
                     const int* rowptr, const int* csr, int Ndst,
                     const float* W1p, const float* b1p,
                     const float* gp, const float* bp,
                     const float* W2p, const float* b2p,
                     float* hin, float* h1, double* gsum, double* gsq,
                     float* xnew, __half* msg_out, hipStream_t stream)
{
    hipMemsetAsync(gsum, 0, 2 * DD2 * sizeof(double), stream); // gsum|gsq contiguous

    int waves = (Ndst + 1) / 2;
    agg_k<<<(waves * 64 + 255) / 256, 256, 0, stream>>>(msg_src, xdst, rowptr, csr, hin, Ndst);

    int g1 = (Ndst + 31) / 32;
    gemm1_bn_k<<<g1, 256, 0, stream>>>(hin, W1p, b1p, h1, gsum, gsq, Ndst);
    gemm2_k<<<g1, 256, 0, stream>>>(h1, gsum, gsq, gp, bp, W2p, b2p, xnew, msg_out, Ndst);
}

extern "C" void kernel_launch(void* const* d_in, const int* in_sizes, int n_in,
                              void* d_out, int out_size, void* d_ws, size_t ws_size,
                              hipStream_t stream)
{
    const float* x_user = (const float*)d_in[0];
    const float* x_item = (const float*)d_in[1];
    const float* W1    = (const float*)d_in[2];   // [3][2][64][128]
    const float* b1    = (const float*)d_in[3];
    const float* gamma = (const float*)d_in[4];
    const float* beta  = (const float*)d_in[5];
    const float* W2    = (const float*)d_in[6];   // [3][2][128][64]
    const float* b2    = (const float*)d_in[7];
    const int* edge = (const int*)d_in[8];        // [2][E]
    const int* pred = (const int*)d_in[9];        // [2][B]
    float* out = (float*)d_out;

    const int* u_idx = edge;
    const int* i_idx = edge + NEDG;

    // ---- workspace bump allocator (256B aligned chunks) ----
    char* p = (char*)d_ws;
    #define ALLOC(ptr, type, count) \
        type* ptr = (type*)p; p += (((size_t)(count) * sizeof(type)) + 255) & ~(size_t)255;

    ALLOC(deg_i, int, NITM)
    ALLOC(deg_u, int, NUSR)
    ALLOC(part_i, int, NITM)
    ALLOC(part_u, int, NUSR)
    ALLOC(bsum_i, int, 128)
    ALLOC(bsum_u, int, 128)
    ALLOC(rowptr_i, int, NITM + 1)
    ALLOC(rowptr_u, int, NUSR + 1)
    ALLOC(cur_i, int, NITM)
    ALLOC(cur_u, int, NUSR)
    ALLOC(csr_i, int, NEDG)          // per-item incident users
    ALLOC(csr_u, int, NEDG)          // per-user incident items
    ALLOC(hin, float, (size_t)NUSR * DD)
    ALLOC(h1, float, (size_t)NUSR * DD2)
    ALLOC(gsum, double, DD2)
    ALLOC(gsq, double, DD2)
    ALLOC(xu0, float, (size_t)NUSR * DD)
    ALLOC(xu1, float, (size_t)NUSR * DD)
    ALLOC(xi0, float, (size_t)NITM * DD)
    ALLOC(xi1, float, (size_t)NITM * DD)
    ALLOC(msg_u, __half, (size_t)NUSR * DD)     // 12.8 MB (single buffer)
    ALLOC(msg_i0, __half, (size_t)NITM * DD)    // 6.4 MB (double-buffered)
    ALLOC(msg_i1, __half, (size_t)NITM * DD)
    #undef ALLOC
    float* xu_buf[2] = {xu0, xu1};
    float* xi_buf[2] = {xi0, xi1};

    // ---- CSR build (once; reused by all 3 layers) ----
    hipMemsetAsync(deg_i, 0, NITM * sizeof(int), stream);
    hipMemsetAsync(deg_u, 0, NUSR * sizeof(int), stream);
    count_k<<<(NEDG + 255) / 256, 256, 0, stream>>>(u_idx, i_idx, deg_u, deg_i);

    int nbi = (NITM + SCAN_B - 1) / SCAN_B;   // 49
    int nbu = (NUSR + SCAN_B - 1) / SCAN_B;   // 98
    scan1_k<<<nbi, SCAN_B, 0, stream>>>(deg_i, part_i, bsum_i, NITM);
    scan2_k<<<1, 128, 0, stream>>>(bsum_i, nbi);
    scan3_k<<<nbi, SCAN_B, 0, stream>>>(deg_i, part_i, bsum_i, rowptr_i, cur_i, NITM);
    scan1_k<<<nbu, SCAN_B, 0, stream>>>(deg_u, part_u, bsum_u, NUSR);
    scan2_k<<<1, 128, 0, stream>>>(bsum_u, nbu);
    scan3_k<<<nbu, SCAN_B, 0, stream>>>(deg_u, part_u, bsum_u, rowptr_u, cur_u, NUSR);
    scatter_k<<<(NEDG + 255) / 256, 256, 0, stream>>>(u_idx, i_idx, cur_i, cur_u, csr_i, csr_u);

    // ---- layer-0 messages from raw inputs ----
    msg0_k<<<(NUSR * 16 + 255) / 256, 256, 0, stream>>>(x_user, msg_u, NUSR * 16);
    msg0_k<<<(NITM * 16 + 255) / 256, 256, 0, stream>>>(x_item, msg_i0, NITM * 16);

    // ---- 3 layers x 2 convs ----
    const float* cu = x_user;
    const float* ci = x_item;
    __half* msgi = msg_i0;
    __half* msgi_alt = msg_i1;
    for (int l = 0; l < 3; l++) {
        size_t o0 = (size_t)l * 2 + 0;   // user->item conv params
        size_t o1 = (size_t)l * 2 + 1;   // item->user conv params
        float* ni = xi_buf[l & 1];
        float* nu = xu_buf[l & 1];
        // conv0 (src=user msgs, dst=item); writes new item msgs to alt buffer
        run_conv(msg_u, ci, rowptr_i, csr_i, NITM,
                 W1 + o0 * DD * DD2, b1 + o0 * DD2, gamma + o0 * DD2, beta + o0 * DD2,
                 W2 + o0 * DD2 * DD, b2 + o0 * DD,
                 hin, h1, gsum, gsq, ni, msgi_alt, stream);
        // conv1 (src=item msgs OLD, dst=user); overwrites msg_u (already consumed)
        run_conv(msgi, cu, rowptr_u, csr_u, NUSR,
                 W1 + o1 * DD * DD2, b1 + o1 * DD2, gamma + o1 * DD2, beta + o1 * DD2,
                 W2 + o1 * DD2 * DD, b2 + o1 * DD,
                 hin, h1, gsum, gsq, nu, msg_u, stream);
        cu = nu; ci = ni;
        __half* tmp = msgi; msgi = msgi_alt; msgi_alt = tmp;
    }

    decode_k<<<(NPRED * 16) / 256, 256, 0, stream>>>(cu, ci, pred, pred + NPRED, out);
}

// Round 5
// 1136.535 us; speedup vs baseline: 3.9097x; 1.1374x over previous
//
#include <hip/hip_runtime.h>
#include <hip/hip_fp16.h>

#define NUSR 100000
#define NITM 50000
#define NEDG 1000000
#define NPRED 250000
#define DD 64
#define DD2 128
#define MSG_EPS 1e-7f
#define BN_EPS 1e-5f
#define SCAN_B 1024

// ================= CSR build (once per call; edges are layer-invariant) ==========

__global__ __launch_bounds__(256) void count_k(
    const int* __restrict__ u_idx, const int* __restrict__ i_idx,
    int* __restrict__ deg_u, int* __restrict__ deg_i)
{
    int base = (blockIdx.x * 256 + threadIdx.x) * 4;
    int u[4], it[4];
    #pragma unroll
    for (int q = 0; q < 4; q++) {
        int e = base + q;
        u[q]  = (e < NEDG) ? u_idx[e] : -1;
        it[q] = (e < NEDG) ? i_idx[e] : -1;
    }
    #pragma unroll
    for (int q = 0; q < 4; q++) if (it[q] >= 0) atomicAdd(&deg_i[it[q]], 1);
    #pragma unroll
    for (int q = 0; q < 4; q++) if (u[q] >= 0) atomicAdd(&deg_u[u[q]], 1);
}

__global__ __launch_bounds__(SCAN_B) void scan1_k(
    const int* __restrict__ deg, int* __restrict__ partial, int* __restrict__ bsum, int n)
{
    __shared__ int s[SCAN_B];
    int tid = threadIdx.x;
    int i = blockIdx.x * SCAN_B + tid;
    s[tid] = (i < n) ? deg[i] : 0;
    __syncthreads();
    for (int off = 1; off < SCAN_B; off <<= 1) {
        int t = (tid >= off) ? s[tid - off] : 0;
        __syncthreads();
        s[tid] += t;
        __syncthreads();
    }
    if (i < n) partial[i] = s[tid];
    if (tid == SCAN_B - 1) bsum[blockIdx.x] = s[tid];
}

__global__ __launch_bounds__(128) void scan2_k(int* __restrict__ bsum, int nb)
{
    __shared__ int s[128];
    int tid = threadIdx.x;
    s[tid] = (tid < nb) ? bsum[tid] : 0;
    __syncthreads();
    for (int off = 1; off < 128; off <<= 1) {
        int t = (tid >= off) ? s[tid - off] : 0;
        __syncthreads();
        s[tid] += t;
        __syncthreads();
    }
    if (tid < nb) bsum[tid] = (tid == 0) ? 0 : s[tid - 1];
}

__global__ __launch_bounds__(SCAN_B) void scan3_k(
    const int* __restrict__ deg, const int* __restrict__ partial,
    const int* __restrict__ bsum, int* __restrict__ rowptr, int* __restrict__ cursor, int n)
{
    int i = blockIdx.x * SCAN_B + threadIdx.x;
    if (i < n) {
        int rs = partial[i] - deg[i] + bsum[blockIdx.x];
        rowptr[i] = rs;
        cursor[i] = rs;
    }
    if (i == 0) rowptr[n] = NEDG;
}

// 4 edges/thread: independent atomic+store chains for latency hiding
__global__ __launch_bounds__(256) void scatter_k(
    const int* __restrict__ u_idx, const int* __restrict__ i_idx,
    int* __restrict__ cur_i, int* __restrict__ cur_u,
    int* __restrict__ csr_i, int* __restrict__ csr_u)
{
    int base = (blockIdx.x * 256 + threadIdx.x) * 4;
    int u[4], it[4], p[4], r[4];
    #pragma unroll
    for (int q = 0; q < 4; q++) {
        int e = base + q;
        u[q]  = (e < NEDG) ? u_idx[e] : -1;
        it[q] = (e < NEDG) ? i_idx[e] : -1;
    }
    #pragma unroll
    for (int q = 0; q < 4; q++) if (it[q] >= 0) p[q] = atomicAdd(&cur_i[it[q]], 1);
    #pragma unroll
    for (int q = 0; q < 4; q++) if (u[q] >= 0) r[q] = atomicAdd(&cur_u[u[q]], 1);
    #pragma unroll
    for (int q = 0; q < 4; q++) if (it[q] >= 0) csr_i[p[q]] = u[q];
    #pragma unroll
    for (int q = 0; q < 4; q++) if (u[q] >= 0) csr_u[r[q]] = it[q];
}

// ========== layer-0 message precompute: msg = half(relu(x)+eps) ==================
__global__ __launch_bounds__(256) void msg0_k(
    const float* __restrict__ x, __half* __restrict__ msg, int n4)
{
    int i = blockIdx.x * 256 + threadIdx.x;
    if (i >= n4) return;
    float4 v = ((const float4*)x)[i];
    __half2 a = __floats2half2_rn(fmaxf(v.x, 0.f) + MSG_EPS, fmaxf(v.y, 0.f) + MSG_EPS);
    __half2 b = __floats2half2_rn(fmaxf(v.z, 0.f) + MSG_EPS, fmaxf(v.w, 0.f) + MSG_EPS);
    ((__half2*)msg)[i * 2]     = a;
    ((__half2*)msg)[i * 2 + 1] = b;
}

// ============ aggregation: 2 rows/wave (32 lanes x half2 each), online softmax ===
#define OS_UPDATE(vx, vy)                                                   \
    {                                                                       \
        float nm0 = fmaxf(mx0, vx);                                         \
        float sc0 = __expf(mx0 - nm0), e0 = __expf(vx - nm0);               \
        d0 = d0 * sc0 + e0; n0 = n0 * sc0 + e0 * (vx); mx0 = nm0;           \
        float nm1 = fmaxf(mx1, vy);                                         \
        float sc1 = __expf(mx1 - nm1), e1 = __expf(vy - nm1);               \
        d1 = d1 * sc1 + e1; n1 = n1 * sc1 + e1 * (vy); mx1 = nm1;           \
    }

__global__ __launch_bounds__(256) void agg_k(
    const __half* __restrict__ msg, const float* __restrict__ xdst,
    const int* __restrict__ rowptr, const int* __restrict__ csr,
    float* __restrict__ hin, int N)
{
    int idx = blockIdx.x * 256 + threadIdx.x;
    int wid = idx >> 6;
    int lane = threadIdx.x & 63;
    int r = wid * 2 + (lane >> 5);      // 2 rows per wave
    int fp = lane & 31;                 // feature-pair index (half2 / float2)
    if (r >= N) return;
    int beg = rowptr[r], end = rowptr[r + 1];
    const __half2* mp = (const __half2*)msg;

    float mx0 = -1e30f, mx1 = -1e30f, d0 = 0.f, d1 = 0.f, n0 = 0.f, n1 = 0.f;
    int j = beg;
    for (; j + 4 <= end; j += 4) {
        int s0 = csr[j], s1 = csr[j + 1], s2 = csr[j + 2], s3 = csr[j + 3];
        __half2 h0 = mp[(size_t)s0 * 32 + fp];
        __half2 h1 = mp[(size_t)s1 * 32 + fp];
        __half2 h2 = mp[(size_t)s2 * 32 + fp];
        __half2 h3 = mp[(size_t)s3 * 32 + fp];
        float2 v0 = __half22float2(h0);
        float2 v1 = __half22float2(h1);
        float2 v2 = __half22float2(h2);
        float2 v3 = __half22float2(h3);
        OS_UPDATE(v0.x, v0.y)
        OS_UPDATE(v1.x, v1.y)
        OS_UPDATE(v2.x, v2.y)
        OS_UPDATE(v3.x, v3.y)
    }
    for (; j < end; j++) {
        float2 v = __half22float2(mp[(size_t)csr[j] * 32 + fp]);
        OS_UPDATE(v.x, v.y)
    }
    float ax = (end > beg) ? n0 / d0 : 0.f;
    float ay = (end > beg) ? n1 / d1 : 0.f;
    float2 xd = ((const float2*)xdst)[(size_t)r * 32 + fp];
    float2 o; o.x = ax + xd.x; o.y = ay + xd.y;
    ((float2*)hin)[(size_t)r * 32 + fp] = o;
}

// ================= GEMM1: h1 = hin @ W1 + b1, accumulate BN stats ===============
// 32-row tile, acc[4][4], k-unrolled x4 with b128 LDS reads (sx stride 68).
__global__ __launch_bounds__(256) void gemm1_bn_k(
    const float* __restrict__ hin, const float* __restrict__ W1,
    const float* __restrict__ b1, float* __restrict__ h1,
    double* __restrict__ gsum, double* __restrict__ gsq, int N)
{
    __shared__ float sW[DD * DD2];          // 32 KB
    __shared__ float sx[32][68];            // 8.5 KB, rows 16B-aligned (272 B)
    __shared__ float sred[2][8][DD2];       // 8 KB

    int t = threadIdx.x;
    for (int i = t; i < DD * DD2 / 4; i += 256)
        ((float4*)sW)[i] = ((const float4*)W1)[i];
    int r0 = blockIdx.x * 32;
    // stage x: 32 rows x 16 quads
    for (int i = t; i < 512; i += 256) {
        int rr = i >> 4, q = i & 15, r = r0 + rr;
        float4 v = make_float4(0.f, 0.f, 0.f, 0.f);
        if (r < N) v = ((const float4*)(hin + (size_t)r * DD))[q];
        *(float4*)&sx[rr][q * 4] = v;
    }
    __syncthreads();

    int tx = t & 31, ty = t >> 5;           // 32 col-groups x 8 row-groups
    float acc[4][4];
    #pragma unroll
    for (int i = 0; i < 4; i++)
        #pragma unroll
        for (int j = 0; j < 4; j++) acc[i][j] = 0.f;

    for (int k = 0; k < DD; k += 4) {
        float4 w0 = ((const float4*)(sW + (k + 0) * DD2))[tx];
        float4 w1 = ((const float4*)(sW + (k + 1) * DD2))[tx];
        float4 w2 = ((const float4*)(sW + (k + 2) * DD2))[tx];
        float4 w3 = ((const float4*)(sW + (k + 3) * DD2))[tx];
        #pragma unroll
        for (int i = 0; i < 4; i++) {
            float4 xv = *(const float4*)&sx[ty * 4 + i][k];
            acc[i][0] = fmaf(xv.x, w0.x, acc[i][0]);
            acc[i][1] = fmaf(xv.x, w0.y, acc[i][1]);
            acc[i][2] = fmaf(xv.x, w0.z, acc[i][2]);
            acc[i][3] = fmaf(xv.x, w0.w, acc[i][3]);
            acc[i][0] = fmaf(xv.y, w1.x, acc[i][0]);
            acc[i][1] = fmaf(xv.y, w1.y, acc[i][1]);
            acc[i][2] = fmaf(xv.y, w1.z, acc[i][2]);
            acc[i][3] = fmaf(xv.y, w1.w, acc[i][3]);
            acc[i][0] = fmaf(xv.z, w2.x, acc[i][0]);
            acc[i][1] = fmaf(xv.z, w2.y, acc[i][1]);
            acc[i][2] = fmaf(xv.z, w2.z, acc[i][2]);
            acc[i][3] = fmaf(xv.z, w2.w, acc[i][3]);
            acc[i][0] = fmaf(xv.w, w3.x, acc[i][0]);
            acc[i][1] = fmaf(xv.w, w3.y, acc[i][1]);
            acc[i][2] = fmaf(xv.w, w3.z, acc[i][2]);
            acc[i][3] = fmaf(xv.w, w3.w, acc[i][3]);
        }
    }

    float4 bb = ((const float4*)b1)[tx];
    float ps[4] = {0,0,0,0}, pq[4] = {0,0,0,0};
    #pragma unroll
    for (int i = 0; i < 4; i++) {
        int r = r0 + ty * 4 + i;
        if (r < N) {
            float4 hv;
            hv.x = acc[i][0] + bb.x; hv.y = acc[i][1] + bb.y;
            hv.z = acc[i][2] + bb.z; hv.w = acc[i][3] + bb.w;
            ((float4*)(h1 + (size_t)r * DD2))[tx] = hv;
            ps[0] += hv.x; pq[0] += hv.x * hv.x;
            ps[1] += hv.y; pq[1] += hv.y * hv.y;
            ps[2] += hv.z; pq[2] += hv.z * hv.z;
            ps[3] += hv.w; pq[3] += hv.w * hv.w;
        }
    }
    #pragma unroll
    for (int j = 0; j < 4; j++) {
        sred[0][ty][tx * 4 + j] = ps[j];
        sred[1][ty][tx * 4 + j] = pq[j];
    }
    __syncthreads();
    if (t < DD2) {
        float s = 0.f, q = 0.f;
        #pragma unroll
        for (int y = 0; y < 8; y++) { s += sred[0][y][t]; q += sred[1][y][t]; }
        atomicAdd(&gsum[t], (double)s);
        atomicAdd(&gsq[t],  (double)q);
    }
}

// ===== GEMM2: xnew = relu( relu(bn(h1)) @ W2 + b2 ), + msg epilogue ==============
// 48-row tile, acc[3][4], tx in [0,16) over 64 cols, k-unrolled x4 (sx stride 132).
__global__ __launch_bounds__(256) void gemm2_k(
    const float* __restrict__ h1,
    const double* __restrict__ gsum, const double* __restrict__ gsq,
    const float* __restrict__ gamma, const float* __restrict__ beta,
    const float* __restrict__ W2, const float* __restrict__ b2,
    float* __restrict__ xnew, __half* __restrict__ msgout, int N)
{
    __shared__ float sW[DD2 * DD];          // 32 KB
    __shared__ float sx[48][132];           // 24.75 KB, rows 16B-aligned (528 B)
    __shared__ float2 sss[DD2];             // 1 KB

    int t = threadIdx.x;
    if (t < DD2) {
        double mean = gsum[t] / (double)N;
        double var  = gsq[t] / (double)N - mean * mean;
        float inv = (float)(1.0 / sqrt(var + (double)BN_EPS));
        float sc = gamma[t] * inv;
        sss[t] = make_float2(sc, beta[t] - (float)mean * sc);
    }
    for (int i = t; i < DD2 * DD / 4; i += 256)
        ((float4*)sW)[i] = ((const float4*)W2)[i];
    __syncthreads();

    int r0 = blockIdx.x * 48;
    // stage x (BN+relu applied): 48 rows x 32 quads; each thread owns col-quad q
    {
        int q = t & 31;                     // fixed col-group per thread
        int rbase = t >> 5;                 // 0..7
        float2 s0 = sss[q * 4 + 0], s1 = sss[q * 4 + 1];
        float2 s2 = sss[q * 4 + 2], s3 = sss[q * 4 + 3];
        #pragma unroll
        for (int ii = 0; ii < 6; ii++) {
            int rr = rbase + ii * 8, r = r0 + rr;
            float4 v = make_float4(0.f, 0.f, 0.f, 0.f);
            if (r < N) {
                v = ((const float4*)(h1 + (size_t)r * DD2))[q];
                v.x = fmaxf(fmaf(v.x, s0.x, s0.y), 0.f);
                v.y = fmaxf(fmaf(v.y, s1.x, s1.y), 0.f);
                v.z = fmaxf(fmaf(v.z, s2.x, s2.y), 0.f);
                v.w = fmaxf(fmaf(v.w, s3.x, s3.y), 0.f);
            }
            *(float4*)&sx[rr][q * 4] = v;
        }
    }
    __syncthreads();

    int tx = t & 15, ty = t >> 4;           // 16 col-groups x 16 row-groups (3 rows)
    float acc[3][4];
    #pragma unroll
    for (int i = 0; i < 3; i++)
        #pragma unroll
        for (int j = 0; j < 4; j++) acc[i][j] = 0.f;

    for (int k = 0; k < DD2; k += 4) {
        float4 w0 = ((const float4*)(sW + (k + 0) * DD))[tx];
        float4 w1 = ((const float4*)(sW + (k + 1) * DD))[tx];
        float4 w2 = ((const float4*)(sW + (k + 2) * DD))[tx];
        float4 w3 = ((const float4*)(sW + (k + 3) * DD))[tx];
        #pragma unroll
        for (int i = 0; i < 3; i++) {
            float4 xv = *(const float4*)&sx[ty * 3 + i][k];
            acc[i][0] = fmaf(xv.x, w0.x, acc[i][0]);
            acc[i][1] = fmaf(xv.x, w0.y, acc[i][1]);
            acc[i][2] = fmaf(xv.x, w0.z, acc[i][2]);
            acc[i][3] = fmaf(xv.x, w0.w, acc[i][3]);
            acc[i][0] = fmaf(xv.y, w1.x, acc[i][0]);
            acc[i][1] = fmaf(xv.y, w1.y, acc[i][1]);
            acc[i][2] = fmaf(xv.y, w1.z, acc[i][2]);
            acc[i][3] = fmaf(xv.y, w1.w, acc[i][3]);
            acc[i][0] = fmaf(xv.z, w2.x, acc[i][0]);
            acc[i][1] = fmaf(xv.z, w2.y, acc[i][1]);
            acc[i][2] = fmaf(xv.z, w2.z, acc[i][2]);
            acc[i][3] = fmaf(xv.z, w2.w, acc[i][3]);
            acc[i][0] = fmaf(xv.w, w3.x, acc[i][0]);
            acc[i][1] = fmaf(xv.w, w3.y, acc[i][1]);
            acc[i][2] = fmaf(xv.w, w3.z, acc[i][2]);
            acc[i][3] = fmaf(xv.w, w3.w, acc[i][3]);
        }
    }
    float4 bb = ((const float4*)b2)[tx];
    #pragma unroll
    for (int i = 0; i < 3; i++) {
        int r = r0 + ty * 3 + i;
        if (r < N) {
            float4 o;
            o.x = fmaxf(acc[i][0] + bb.x, 0.f);
            o.y = fmaxf(acc[i][1] + bb.y, 0.f);
            o.z = fmaxf(acc[i][2] + bb.z, 0.f);
            o.w = fmaxf(acc[i][3] + bb.w, 0.f);
            ((float4*)(xnew + (size_t)r * DD))[tx] = o;
            __half2 ha = __floats2half2_rn(o.x + MSG_EPS, o.y + MSG_EPS);
            __half2 hb = __floats2half2_rn(o.z + MSG_EPS, o.w + MSG_EPS);
            ((__half2*)msgout)[(size_t)r * 32 + tx * 2]     = ha;
            ((__half2*)msgout)[(size_t)r * 32 + tx * 2 + 1] = hb;
        }
    }
}

// ================= decoder ========================================================
__global__ __launch_bounds__(256) void decode_k(
    const float* __restrict__ xu, const float* __restrict__ xi,
    const int* __restrict__ pu, const int* __restrict__ pi,
    float* __restrict__ out)
{
    int idx = blockIdx.x * 256 + threadIdx.x;
    int b = idx >> 4, lane = idx & 15;
    if (b >= NPRED) return;
    int u = pu[b], it = pi[b];
    float4 a = ((const float4*)(xu + (size_t)u * DD))[lane];
    float4 c = ((const float4*)(xi + (size_t)it * DD))[lane];
    float s = a.x * c.x + a.y * c.y + a.z * c.z + a.w * c.w;
    #pragma unroll
    for (int off = 8; off; off >>= 1) s += __shfl_down(s, off, 16);
    if (lane == 0) out[b] = s;
}

// ================= host-side conv driver ==========================================
static void run_conv(const __half* msg_src, const float* xdst,
                     const int* rowptr, const int* csr, int Ndst,
                     const float* W1p, const float* b1p,
                     const float* gp, const float* bp,
                     const float* W2p, const float* b2p,
                     float* hin, float* h1, double* gsum, double* gsq,
                     float* xnew, __half* msg_out, hipStream_t stream)
{
    hipMemsetAsync(gsum, 0, 2 * DD2 * sizeof(double), stream); // gsum|gsq contiguous

    int waves = (Ndst + 1) / 2;
    agg_k<<<(waves * 64 + 255) / 256, 256, 0, stream>>>(msg_src, xdst, rowptr, csr, hin, Ndst);

    gemm1_bn_k<<<(Ndst + 31) / 32, 256, 0, stream>>>(hin, W1p, b1p, h1, gsum, gsq, Ndst);
    gemm2_k<<<(Ndst + 47) / 48, 256, 0, stream>>>(h1, gsum, gsq, gp, bp, W2p, b2p,
                                                  xnew, msg_out, Ndst);
}

extern "C" void kernel_launch(void* const* d_in, const int* in_sizes, int n_in,
                              void* d_out, int out_size, void* d_ws, size_t ws_size,
                              hipStream_t stream)
{
    const float* x_user = (const float*)d_in[0];
    const float* x_item = (const float*)d_in[1];
    const float* W1    = (const float*)d_in[2];   // [3][2][64][128]
    const float* b1    = (const float*)d_in[3];
    const float* gamma = (const float*)d_in[4];
    const float* beta  = (const float*)d_in[5];
    const float* W2    = (const float*)d_in[6];   // [3][2][128][64]
    const float* b2    = (const float*)d_in[7];
    const int* edge = (const int*)d_in[8];        // [2][E]
    const int* pred = (const int*)d_in[9];        // [2][B]
    float* out = (float*)d_out;

    const int* u_idx = edge;
    const int* i_idx = edge + NEDG;

    // ---- workspace bump allocator (256B aligned chunks) ----
    char* p = (char*)d_ws;
    #define ALLOC(ptr, type, count) \
        type* ptr = (type*)p; p += (((size_t)(count) * sizeof(type)) + 255) & ~(size_t)255;

    ALLOC(deg_i, int, NITM)
    ALLOC(deg_u, int, NUSR)
    ALLOC(part_i, int, NITM)
    ALLOC(part_u, int, NUSR)
    ALLOC(bsum_i, int, 128)
    ALLOC(bsum_u, int, 128)
    ALLOC(rowptr_i, int, NITM + 1)
    ALLOC(rowptr_u, int, NUSR + 1)
    ALLOC(cur_i, int, NITM)
    ALLOC(cur_u, int, NUSR)
    ALLOC(csr_i, int, NEDG)          // per-item incident users
    ALLOC(csr_u, int, NEDG)          // per-user incident items
    ALLOC(hin, float, (size_t)NUSR * DD)
    ALLOC(h1, float, (size_t)NUSR * DD2)
    ALLOC(gsum, double, DD2)
    ALLOC(gsq, double, DD2)
    ALLOC(xu0, float, (size_t)NUSR * DD)
    ALLOC(xu1, float, (size_t)NUSR * DD)
    ALLOC(xi0, float, (size_t)NITM * DD)
    ALLOC(xi1, float, (size_t)NITM * DD)
    ALLOC(msg_u, __half, (size_t)NUSR * DD)     // 12.8 MB (single buffer)
    ALLOC(msg_i0, __half, (size_t)NITM * DD)    // 6.4 MB (double-buffered)
    ALLOC(msg_i1, __half, (size_t)NITM * DD)
    #undef ALLOC
    float* xu_buf[2] = {xu0, xu1};
    float* xi_buf[2] = {xi0, xi1};

    // ---- CSR build (once; reused by all 3 layers) ----
    hipMemsetAsync(deg_i, 0, NITM * sizeof(int), stream);
    hipMemsetAsync(deg_u, 0, NUSR * sizeof(int), stream);
    int eb4 = (NEDG / 4 + 255) / 256;
    count_k<<<eb4, 256, 0, stream>>>(u_idx, i_idx, deg_u, deg_i);

    int nbi = (NITM + SCAN_B - 1) / SCAN_B;   // 49
    int nbu = (NUSR + SCAN_B - 1) / SCAN_B;   // 98
    scan1_k<<<nbi, SCAN_B, 0, stream>>>(deg_i, part_i, bsum_i, NITM);
    scan2_k<<<1, 128, 0, stream>>>(bsum_i, nbi);
    scan3_k<<<nbi, SCAN_B, 0, stream>>>(deg_i, part_i, bsum_i, rowptr_i, cur_i, NITM);
    scan1_k<<<nbu, SCAN_B, 0, stream>>>(deg_u, part_u, bsum_u, NUSR);
    scan2_k<<<1, 128, 0, stream>>>(bsum_u, nbu);
    scan3_k<<<nbu, SCAN_B, 0, stream>>>(deg_u, part_u, bsum_u, rowptr_u, cur_u, NUSR);
    scatter_k<<<eb4, 256, 0, stream>>>(u_idx, i_idx, cur_i, cur_u, csr_i, csr_u);

    // ---- layer-0 messages from raw inputs ----
    msg0_k<<<(NUSR * 16 + 255) / 256, 256, 0, stream>>>(x_user, msg_u, NUSR * 16);
    msg0_k<<<(NITM * 16 + 255) / 256, 256, 0, stream>>>(x_item, msg_i0, NITM * 16);

    // ---- 3 layers x 2 convs ----
    const float* cu = x_user;
    const float* ci = x_item;
    __half* msgi = msg_i0;
    __half* msgi_alt = msg_i1;
    for (int l = 0; l < 3; l++) {
        size_t o0 = (size_t)l * 2 + 0;   // user->item conv params
        size_t o1 = (size_t)l * 2 + 1;   // item->user conv params
        float* ni = xi_buf[l & 1];
        float* nu = xu_buf[l & 1];
        // conv0 (src=user msgs, dst=item); writes new item msgs to alt buffer
        run_conv(msg_u, ci, rowptr_i, csr_i, NITM,
                 W1 + o0 * DD * DD2, b1 + o0 * DD2, gamma + o0 * DD2, beta + o0 * DD2,
                 W2 + o0 * DD2 * DD, b2 + o0 * DD,
                 hin, h1, gsum, gsq, ni, msgi_alt, stream);
        // conv1 (src=item msgs OLD, dst=user); overwrites msg_u (already consumed)
        run_conv(msgi, cu, rowptr_u, csr_u, NUSR,
                 W1 + o1 * DD * DD2, b1 + o1 * DD2, gamma + o1 * DD2, beta + o1 * DD2,
                 W2 + o1 * DD2 * DD, b2 + o1 * DD,
                 hin, h1, gsum, gsq, nu, msg_u, stream);
        cu = nu; ci = ni;
        __half* tmp = msgi; msgi = msgi_alt; msgi_alt = tmp;
    }

    decode_k<<<(NPRED * 16) / 256, 256, 0, stream>>>(cu, ci, pred, pred + NPRED, out);
}

// Round 7
// 904.790 us; speedup vs baseline: 4.9111x; 1.2561x over previous
//
#include <hip/hip_runtime.h>
#include <hip/hip_fp16.h>

#define NUSR 100000
#define NITM 50000
#define NEDG 1000000
#define NPRED 250000
#define DD 64
#define DD2 128
#define MSG_EPS 1e-7f
#define BN_EPS 1e-5f
#define SCAN_B 1024

typedef _Float16 f16x8 __attribute__((ext_vector_type(8)));
typedef float f32x4 __attribute__((ext_vector_type(4)));

// ================= CSR build (once per call; edges are layer-invariant) ==========

__global__ __launch_bounds__(256) void count_k(
    const int* __restrict__ u_idx, const int* __restrict__ i_idx,
    int* __restrict__ deg_u, int* __restrict__ deg_i)
{
    int base = (blockIdx.x * 256 + threadIdx.x) * 2;
    int u[2], it[2];
    #pragma unroll
    for (int q = 0; q < 2; q++) {
        int e = base + q;
        u[q]  = (e < NEDG) ? u_idx[e] : -1;
        it[q] = (e < NEDG) ? i_idx[e] : -1;
    }
    #pragma unroll
    for (int q = 0; q < 2; q++) if (it[q] >= 0) atomicAdd(&deg_i[it[q]], 1);
    #pragma unroll
    for (int q = 0; q < 2; q++) if (u[q] >= 0) atomicAdd(&deg_u[u[q]], 1);
}

__global__ __launch_bounds__(SCAN_B) void scan1_k(
    const int* __restrict__ deg, int* __restrict__ partial, int* __restrict__ bsum, int n)
{
    __shared__ int s[SCAN_B];
    int tid = threadIdx.x;
    int i = blockIdx.x * SCAN_B + tid;
    s[tid] = (i < n) ? deg[i] : 0;
    __syncthreads();
    for (int off = 1; off < SCAN_B; off <<= 1) {
        int t = (tid >= off) ? s[tid - off] : 0;
        __syncthreads();
        s[tid] += t;
        __syncthreads();
    }
    if (i < n) partial[i] = s[tid];
    if (tid == SCAN_B - 1) bsum[blockIdx.x] = s[tid];
}

__global__ __launch_bounds__(128) void scan2_k(int* __restrict__ bsum, int nb)
{
    __shared__ int s[128];
    int tid = threadIdx.x;
    s[tid] = (tid < nb) ? bsum[tid] : 0;
    __syncthreads();
    for (int off = 1; off < 128; off <<= 1) {
        int t = (tid >= off) ? s[tid - off] : 0;
        __syncthreads();
        s[tid] += t;
        __syncthreads();
    }
    if (tid < nb) bsum[tid] = (tid == 0) ? 0 : s[tid - 1];
}

__global__ __launch_bounds__(SCAN_B) void scan3_k(
    const int* __restrict__ deg, const int* __restrict__ partial,
    const int* __restrict__ bsum, int* __restrict__ rowptr, int* __restrict__ cursor, int n)
{
    int i = blockIdx.x * SCAN_B + threadIdx.x;
    if (i < n) {
        int rs = partial[i] - deg[i] + bsum[blockIdx.x];
        rowptr[i] = rs;
        cursor[i] = rs;
    }
    if (i == 0) rowptr[n] = NEDG;
}

__global__ __launch_bounds__(256) void scatter_k(
    const int* __restrict__ u_idx, const int* __restrict__ i_idx,
    int* __restrict__ cur_i, int* __restrict__ cur_u,
    int* __restrict__ csr_i, int* __restrict__ csr_u)
{
    int base = (blockIdx.x * 256 + threadIdx.x) * 2;
    int u[2], it[2], p[2], r[2];
    #pragma unroll
    for (int q = 0; q < 2; q++) {
        int e = base + q;
        u[q]  = (e < NEDG) ? u_idx[e] : -1;
        it[q] = (e < NEDG) ? i_idx[e] : -1;
    }
    #pragma unroll
    for (int q = 0; q < 2; q++) if (it[q] >= 0) p[q] = atomicAdd(&cur_i[it[q]], 1);
    #pragma unroll
    for (int q = 0; q < 2; q++) if (u[q] >= 0) r[q] = atomicAdd(&cur_u[u[q]], 1);
    #pragma unroll
    for (int q = 0; q < 2; q++) if (it[q] >= 0) csr_i[p[q]] = u[q];
    #pragma unroll
    for (int q = 0; q < 2; q++) if (u[q] >= 0) csr_u[r[q]] = it[q];
}

// ========== layer-0 message precompute: msg = half(relu(x)+eps) ==================
__global__ __launch_bounds__(256) void msg0_k(
    const float* __restrict__ x, __half* __restrict__ msg, int n4)
{
    int i = blockIdx.x * 256 + threadIdx.x;
    if (i >= n4) return;
    float4 v = ((const float4*)x)[i];
    __half2 a = __floats2half2_rn(fmaxf(v.x, 0.f) + MSG_EPS, fmaxf(v.y, 0.f) + MSG_EPS);
    __half2 b = __floats2half2_rn(fmaxf(v.z, 0.f) + MSG_EPS, fmaxf(v.w, 0.f) + MSG_EPS);
    ((__half2*)msg)[i * 2]     = a;
    ((__half2*)msg)[i * 2 + 1] = b;
}

// ========== weight convert+transpose to fp16 (once per call) =====================
// W1 [6][64][128] -> W1t [6][128][64];  W2 [6][128][64] -> W2t [6][64][128]
__global__ __launch_bounds__(256) void wconv_k(
    const float* __restrict__ W1, const float* __restrict__ W2,
    __half* __restrict__ W1t, __half* __restrict__ W2t)
{
    int idx = blockIdx.x * 256 + threadIdx.x;
    if (idx >= 6 * 8192) return;
    int m = idx >> 13, rem = idx & 8191;
    {   // W1
        int k = rem >> 7, c = rem & 127;
        W1t[m * 8192 + c * 64 + k] = __float2half(W1[idx]);
    }
    {   // W2
        int k = rem >> 6, c = rem & 63;
        W2t[m * 8192 + c * 128 + k] = __float2half(W2[idx]);
    }
}

// ============ aggregation: 4 rows/wave (16 lanes x half4), online softmax ========
// msg row = 64 halves = 128 B = 16 uint2; fp in [0,16)
#define OS1(mx,d,n,v) { float nm=fmaxf(mx,v); float sc=__expf(mx-nm); float e=__expf((v)-nm); \
                        d=d*sc+e; n=n*sc+e*(v); mx=nm; }
#define UPD(u) { float2 va=__half22float2(*(__half2*)&(u).x); \
                 float2 vb=__half22float2(*(__half2*)&(u).y); \
                 OS1(mxA,dA,nA,va.x) OS1(mxB,dB,nB,va.y) \
                 OS1(mxC,dC,nC,vb.x) OS1(mxD,dD,nD,vb.y) }

__global__ __launch_bounds__(256) void agg_k(
    const __half* __restrict__ msg, const float* __restrict__ xdst,
    const int* __restrict__ rowptr, const int* __restrict__ csr,
    __half* __restrict__ hin, int N)
{
    int wid = (blockIdx.x * 256 + threadIdx.x) >> 6;
    int lane = threadIdx.x & 63;
    int r = wid * 4 + (lane >> 4);
    int fp = lane & 15;                 // feature quad (4 halves = 8 B)
    if (r >= N) return;
    int beg = rowptr[r], end = rowptr[r + 1];
    const uint2* mp = (const uint2*)msg;

    float mxA=-1e30f,mxB=-1e30f,mxC=-1e30f,mxD=-1e30f;
    float dA=0.f,dB=0.f,dC=0.f,dD=0.f,nA=0.f,nB=0.f,nC=0.f,nD=0.f;
    int j = beg;
    for (; j + 4 <= end; j += 4) {
        int s0=csr[j], s1=csr[j+1], s2=csr[j+2], s3=csr[j+3];
        uint2 u0 = mp[(size_t)s0*16+fp];
        uint2 u1 = mp[(size_t)s1*16+fp];
        uint2 u2 = mp[(size_t)s2*16+fp];
        uint2 u3 = mp[(size_t)s3*16+fp];
        UPD(u0) UPD(u1) UPD(u2) UPD(u3)
    }
    for (; j < end; j++) {
        uint2 u = mp[(size_t)csr[j]*16+fp];
        UPD(u)
    }
    bool nz = end > beg;
    float aA = nz ? nA/dA : 0.f;
    float aB = nz ? nB/dB : 0.f;
    float aC = nz ? nC/dC : 0.f;
    float aD = nz ? nD/dD : 0.f;
    float4 xd = ((const float4*)xdst)[(size_t)r*16 + fp];
    __half2 h01 = __floats2half2_rn(aA+xd.x, aB+xd.y);
    __half2 h23 = __floats2half2_rn(aC+xd.z, aD+xd.w);
    uint2 o; o.x = *(unsigned int*)&h01; o.y = *(unsigned int*)&h23;
    ((uint2*)hin)[(size_t)r*16+fp] = o;
}

// ===== GEMM1 (MFMA fp16): h1 = hin @ W1 + b1 (fp32 out), BN partial stats ========
// block tile 64 rows x 128 cols, K=64 (2 ksteps of 32). 4 waves; wave w owns cols
// [w*32, w*32+32). A[m=lane&15][k=quad*8+j]; C/D col=lane&15, row=quad*4+reg.
__global__ __launch_bounds__(256) void gemm1_bn_k(
    const __half* __restrict__ hin, const __half* __restrict__ W1t,  // [128][64] f16
    const float* __restrict__ b1, float* __restrict__ h1,
    double* __restrict__ gsum, double* __restrict__ gsq, int N)
{
    __shared__ _Float16 sA[64][72];      // 9.2 KB
    __shared__ _Float16 sB[128][72];     // 18.4 KB
    __shared__ float sredS[4][128];      // 2 KB
    __shared__ float sredQ[4][128];      // 2 KB

    int t = threadIdx.x;
    int r0 = blockIdx.x * 64;
    // stage W1t: 128 rows x 8 float4
    for (int i = t; i < 1024; i += 256) {
        int row = i >> 3, c8 = i & 7;
        *(float4*)&sB[row][c8 * 8] = ((const float4*)W1t)[i];
    }
    // stage hin: 64 rows x 8 float4 (fp16 rows of 64)
    for (int i = t; i < 512; i += 256) {
        int rr = i >> 3, c8 = i & 7;
        int r = r0 + rr;
        float4 v = make_float4(0.f, 0.f, 0.f, 0.f);
        if (r < N) v = ((const float4*)hin)[(size_t)r * 8 + c8];
        *(float4*)&sA[rr][c8 * 8] = v;
    }
    __syncthreads();

    int w = t >> 6, lane = t & 63, q = lane >> 4, ln = lane & 15;

    f16x8 afr[4][2], bfr[2][2];
    #pragma unroll
    for (int rt = 0; rt < 4; rt++)
        #pragma unroll
        for (int ks = 0; ks < 2; ks++)
            afr[rt][ks] = *(const f16x8*)&sA[rt * 16 + ln][ks * 32 + q * 8];
    #pragma unroll
    for (int ct = 0; ct < 2; ct++)
        #pragma unroll
        for (int ks = 0; ks < 2; ks++)
            bfr[ct][ks] = *(const f16x8*)&sB[w * 32 + ct * 16 + ln][ks * 32 + q * 8];

    f32x4 acc[4][2];
    #pragma unroll
    for (int rt = 0; rt < 4; rt++)
        #pragma unroll
        for (int ct = 0; ct < 2; ct++)
            acc[rt][ct] = (f32x4){0.f, 0.f, 0.f, 0.f};

    #pragma unroll
    for (int rt = 0; rt < 4; rt++)
        #pragma unroll
        for (int ct = 0; ct < 2; ct++) {
            acc[rt][ct] = __builtin_amdgcn_mfma_f32_16x16x32_f16(
                afr[rt][0], bfr[ct][0], acc[rt][ct], 0, 0, 0);
            acc[rt][ct] = __builtin_amdgcn_mfma_f32_16x16x32_f16(
                afr[rt][1], bfr[ct][1], acc[rt][ct], 0, 0, 0);
        }

    float b1c0 = b1[w * 32 + ln];
    float b1c1 = b1[w * 32 + 16 + ln];
    float ps0 = 0.f, pq0 = 0.f, ps1 = 0.f, pq1 = 0.f;
    #pragma unroll
    for (int rt = 0; rt < 4; rt++) {
        #pragma unroll
        for (int i = 0; i < 4; i++) {
            int r = r0 + rt * 16 + q * 4 + i;
            if (r < N) {
                float h0 = acc[rt][0][i] + b1c0;
                float h1v = acc[rt][1][i] + b1c1;
                h1[(size_t)r * DD2 + w * 32 + ln] = h0;
                h1[(size_t)r * DD2 + w * 32 + 16 + ln] = h1v;
                ps0 += h0; pq0 += h0 * h0;
                ps1 += h1v; pq1 += h1v * h1v;
            }
        }
    }
    sredS[q][w * 32 + ln] = ps0;  sredS[q][w * 32 + 16 + ln] = ps1;
    sredQ[q][w * 32 + ln] = pq0;  sredQ[q][w * 32 + 16 + ln] = pq1;
    __syncthreads();
    if (t < 128) {
        float s = 0.f, qq = 0.f;
        #pragma unroll
        for (int k = 0; k < 4; k++) { s += sredS[k][t]; qq += sredQ[k][t]; }
        atomicAdd(&gsum[t], (double)s);
        atomicAdd(&gsq[t],  (double)qq);
    }
}

// ===== GEMM2 (MFMA fp16): xnew = relu(relu(bn(h1)) @ W2 + b2) + msg epilogue =====
// block tile 64 rows x 64 cols, K=128 (4 ksteps). wave w owns cols [w*16, w*16+16).
__global__ __launch_bounds__(256) void gemm2_k(
    const float* __restrict__ h1,
    const double* __restrict__ gsum, const double* __restrict__ gsq,
    const float* __restrict__ gamma, const float* __restrict__ beta,
    const __half* __restrict__ W2t,  // [64][128] f16 (n-major)
    const float* __restrict__ b2,
    float* __restrict__ xnew, __half* __restrict__ msgout, int N)
{
    __shared__ _Float16 sA[64][136];    // 17.4 KB
    __shared__ _Float16 sB[64][136];    // 17.4 KB
    __shared__ float2 sss[DD2];         // 1 KB

    int t = threadIdx.x;
    if (t < 128) {
        double mean = gsum[t] / (double)N;
        double var  = gsq[t] / (double)N - mean * mean;
        float inv = (float)(1.0 / sqrt(var + (double)BN_EPS));
        float sc = gamma[t] * inv;
        sss[t] = make_float2(sc, beta[t] - (float)mean * sc);
    }
    // stage W2t: 64 rows x 16 float4
    for (int i = t; i < 1024; i += 256) {
        int row = i >> 4, c8 = i & 15;
        *(float4*)&sB[row][c8 * 8] = ((const float4*)W2t)[i];
    }
    __syncthreads();

    int r0 = blockIdx.x * 64;
    // stage h1 with BN + relu -> fp16: 64 rows x 32 float4
    for (int i = t; i < 2048; i += 256) {
        int rr = i >> 5, c4 = i & 31;
        int r = r0 + rr;
        float4 v = make_float4(0.f, 0.f, 0.f, 0.f);
        if (r < N) {
            v = ((const float4*)h1)[(size_t)r * 32 + c4];
            float2 s0 = sss[c4 * 4], s1 = sss[c4 * 4 + 1];
            float2 s2 = sss[c4 * 4 + 2], s3 = sss[c4 * 4 + 3];
            v.x = fmaxf(fmaf(v.x, s0.x, s0.y), 0.f);
            v.y = fmaxf(fmaf(v.y, s1.x, s1.y), 0.f);
            v.z = fmaxf(fmaf(v.z, s2.x, s2.y), 0.f);
            v.w = fmaxf(fmaf(v.w, s3.x, s3.y), 0.f);
        }
        __half2 a = __floats2half2_rn(v.x, v.y);
        __half2 b = __floats2half2_rn(v.z, v.w);
        uint2 o; o.x = *(unsigned int*)&a; o.y = *(unsigned int*)&b;
        *(uint2*)&sA[rr][c4 * 4] = o;
    }
    __syncthreads();

    int w = t >> 6, lane = t & 63, q = lane >> 4, ln = lane & 15;
    f32x4 acc[4];
    #pragma unroll
    for (int rt = 0; rt < 4; rt++) acc[rt] = (f32x4){0.f, 0.f, 0.f, 0.f};

    #pragma unroll
    for (int ks = 0; ks < 4; ks++) {
        f16x8 bf = *(const f16x8*)&sB[w * 16 + ln][ks * 32 + q * 8];
        #pragma unroll
        for (int rt = 0; rt < 4; rt++) {
            f16x8 af = *(const f16x8*)&sA[rt * 16 + ln][ks * 32 + q * 8];
            acc[rt] = __builtin_amdgcn_mfma_f32_16x16x32_f16(af, bf, acc[rt], 0, 0, 0);
        }
    }

    int c = w * 16 + ln;
    float bb = b2[c];
    #pragma unroll
    for (int rt = 0; rt < 4; rt++) {
        #pragma unroll
        for (int i = 0; i < 4; i++) {
            int r = r0 + rt * 16 + q * 4 + i;
            if (r < N) {
                float o = fmaxf(acc[rt][i] + bb, 0.f);
                xnew[(size_t)r * DD + c] = o;
                msgout[(size_t)r * DD + c] = __float2half(o + MSG_EPS);
            }
        }
    }
}

// ================= decoder ========================================================
__global__ __launch_bounds__(256) void decode_k(
    const float* __restrict__ xu, const float* __restrict__ xi,
    const int* __restrict__ pu, const int* __restrict__ pi,
    float* __restrict__ out)
{
    int idx = blockIdx.x * 256 + threadIdx.x;
    int b = idx >> 4, lane = idx & 15;
    if (b >= NPRED) return;
    int u = pu[b], it = pi[b];
    float4 a = ((const float4*)(xu + (size_t)u * DD))[lane];
    float4 c = ((const float4*)(xi + (size_t)it * DD))[lane];
    float s = a.x * c.x + a.y * c.y + a.z * c.z + a.w * c.w;
    #pragma unroll
    for (int off = 8; off; off >>= 1) s += __shfl_down(s, off, 16);
    if (lane == 0) out[b] = s;
}

// ================= host-side conv driver ==========================================
static void run_conv(const __half* msg_src, const float* xdst,
                     const int* rowptr, const int* csr, int Ndst,
                     const __half* W1tp, const float* b1p,
                     const float* gp, const float* bp,
                     const __half* W2tp, const float* b2p,
                     __half* hin, float* h1, double* gs, double* gq,
                     float* xnew, __half* msg_out, hipStream_t stream)
{
    agg_k<<<(Ndst + 15) / 16, 256, 0, stream>>>(msg_src, xdst, rowptr, csr, hin, Ndst);
    gemm1_bn_k<<<(Ndst + 63) / 64, 256, 0, stream>>>(hin, W1tp, b1p, h1, gs, gq, Ndst);
    gemm2_k<<<(Ndst + 63) / 64, 256, 0, stream>>>(h1, gs, gq, gp, bp, W2tp, b2p,
                                                  xnew, msg_out, Ndst);
}

extern "C" void kernel_launch(void* const* d_in, const int* in_sizes, int n_in,
                              void* d_out, int out_size, void* d_ws, size_t ws_size,
                              hipStream_t stream)
{
    const float* x_user = (const float*)d_in[0];
    const float* x_item = (const float*)d_in[1];
    const float* W1    = (const float*)d_in[2];   // [3][2][64][128]
    const float* b1    = (const float*)d_in[3];
    const float* gamma = (const float*)d_in[4];
    const float* beta  = (const float*)d_in[5];
    const float* W2    = (const float*)d_in[6];   // [3][2][128][64]
    const float* b2    = (const float*)d_in[7];
    const int* edge = (const int*)d_in[8];        // [2][E]
    const int* pred = (const int*)d_in[9];        // [2][B]
    float* out = (float*)d_out;

    const int* u_idx = edge;
    const int* i_idx = edge + NEDG;

    // ---- workspace bump allocator (256B aligned chunks) ----
    char* p = (char*)d_ws;
    #define ALLOC(ptr, type, count) \
        type* ptr = (type*)p; p += (((size_t)(count) * sizeof(type)) + 255) & ~(size_t)255;

    ALLOC(deg_i, int, NITM)
    ALLOC(deg_u, int, NUSR)
    ALLOC(part_i, int, NITM)
    ALLOC(part_u, int, NUSR)
    ALLOC(bsum_i, int, 128)
    ALLOC(bsum_u, int, 128)
    ALLOC(rowptr_i, int, NITM + 1)
    ALLOC(rowptr_u, int, NUSR + 1)
    ALLOC(cur_i, int, NITM)
    ALLOC(cur_u, int, NUSR)
    ALLOC(csr_i, int, NEDG)          // per-item incident users
    ALLOC(csr_u, int, NEDG)          // per-user incident items
    ALLOC(hin, __half, (size_t)NUSR * DD)
    ALLOC(h1, float, (size_t)NUSR * DD2)
    ALLOC(gsumAll, double, 12 * 256)             // 6 convs x (gsum[128]|gsq[128])
    ALLOC(W1t, __half, 6 * 8192)
    ALLOC(W2t, __half, 6 * 8192)
    ALLOC(xu0, float, (size_t)NUSR * DD)
    ALLOC(xu1, float, (size_t)NUSR * DD)
    ALLOC(xi0, float, (size_t)NITM * DD)
    ALLOC(xi1, float, (size_t)NITM * DD)
    ALLOC(msg_u, __half, (size_t)NUSR * DD)
    ALLOC(msg_i0, __half, (size_t)NITM * DD)
    ALLOC(msg_i1, __half, (size_t)NITM * DD)
    #undef ALLOC
    float* xu_buf[2] = {xu0, xu1};
    float* xi_buf[2] = {xi0, xi1};

    // ---- CSR build + converts (once; reused by all 3 layers) ----
    hipMemsetAsync(deg_i, 0, NITM * sizeof(int), stream);
    hipMemsetAsync(deg_u, 0, NUSR * sizeof(int), stream);
    hipMemsetAsync(gsumAll, 0, 12 * 256 * sizeof(double), stream);
    int eb2 = (NEDG / 2 + 255) / 256;
    count_k<<<eb2, 256, 0, stream>>>(u_idx, i_idx, deg_u, deg_i);

    int nbi = (NITM + SCAN_B - 1) / SCAN_B;   // 49
    int nbu = (NUSR + SCAN_B - 1) / SCAN_B;   // 98
    scan1_k<<<nbi, SCAN_B, 0, stream>>>(deg_i, part_i, bsum_i, NITM);
    scan2_k<<<1, 128, 0, stream>>>(bsum_i, nbi);
    scan3_k<<<nbi, SCAN_B, 0, stream>>>(deg_i, part_i, bsum_i, rowptr_i, cur_i, NITM);
    scan1_k<<<nbu, SCAN_B, 0, stream>>>(deg_u, part_u, bsum_u, NUSR);
    scan2_k<<<1, 128, 0, stream>>>(bsum_u, nbu);
    scan3_k<<<nbu, SCAN_B, 0, stream>>>(deg_u, part_u, bsum_u, rowptr_u, cur_u, NUSR);
    scatter_k<<<eb2, 256, 0, stream>>>(u_idx, i_idx, cur_i, cur_u, csr_i, csr_u);

    wconv_k<<<(6 * 8192 + 255) / 256, 256, 0, stream>>>(W1, W2, W1t, W2t);
    msg0_k<<<(NUSR * 16 + 255) / 256, 256, 0, stream>>>(x_user, msg_u, NUSR * 16);
    msg0_k<<<(NITM * 16 + 255) / 256, 256, 0, stream>>>(x_item, msg_i0, NITM * 16);

    // ---- 3 layers x 2 convs ----
    const float* cu = x_user;
    const float* ci = x_item;
    __half* msgi = msg_i0;
    __half* msgi_alt = msg_i1;
    for (int l = 0; l < 3; l++) {
        int o0 = l * 2 + 0;   // user->item conv params
        int o1 = l * 2 + 1;   // item->user conv params
        float* ni = xi_buf[l & 1];
        float* nu = xu_buf[l & 1];
        // conv0 (src=user msgs, dst=item); writes new item msgs to alt buffer
        run_conv(msg_u, ci, rowptr_i, csr_i, NITM,
                 W1t + (size_t)o0 * 8192, b1 + (size_t)o0 * DD2,
                 gamma + (size_t)o0 * DD2, beta + (size_t)o0 * DD2,
                 W2t + (size_t)o0 * 8192, b2 + (size_t)o0 * DD,
                 hin, h1, gsumAll + o0 * 256, gsumAll + o0 * 256 + 128,
                 ni, msgi_alt, stream);
        // conv1 (src=item msgs OLD, dst=user); overwrites msg_u (already consumed)
        run_conv(msgi, cu, rowptr_u, csr_u, NUSR,
                 W1t + (size_t)o1 * 8192, b1 + (size_t)o1 * DD2,
                 gamma + (size_t)o1 * DD2, beta + (size_t)o1 * DD2,
                 W2t + (size_t)o1 * 8192, b2 + (size_t)o1 * DD,
                 hin, h1, gsumAll + o1 * 256, gsumAll + o1 * 256 + 128,
                 nu, msg_u, stream);
        cu = nu; ci = ni;
        __half* tmp = msgi; msgi = msgi_alt; msgi_alt = tmp;
    }

    decode_k<<<(NPRED * 16) / 256, 256, 0, stream>>>(cu, ci, pred, pred + NPRED, out);
}

// Round 8
// 864.709 us; speedup vs baseline: 5.1387x; 1.0464x over previous
//
#include <hip/hip_runtime.h>
#include <hip/hip_fp16.h>

#define NUSR 100000
#define NITM 50000
#define NEDG 1000000
#define NPRED 250000
#define DD 64
#define DD2 128
#define MSG_EPS 1e-7f
#define BN_EPS 1e-5f
#define SCAN_B 1024

typedef _Float16 f16x8 __attribute__((ext_vector_type(8)));
typedef float f32x4 __attribute__((ext_vector_type(4)));

// ================= CSR build (once per call; edges are layer-invariant) ==========

__global__ __launch_bounds__(256) void count_k(
    const int* __restrict__ u_idx, const int* __restrict__ i_idx,
    int* __restrict__ deg_u, int* __restrict__ deg_i)
{
    int base = (blockIdx.x * 256 + threadIdx.x) * 2;
    int u[2], it[2];
    #pragma unroll
    for (int q = 0; q < 2; q++) {
        int e = base + q;
        u[q]  = (e < NEDG) ? u_idx[e] : -1;
        it[q] = (e < NEDG) ? i_idx[e] : -1;
    }
    #pragma unroll
    for (int q = 0; q < 2; q++) if (it[q] >= 0) atomicAdd(&deg_i[it[q]], 1);
    #pragma unroll
    for (int q = 0; q < 2; q++) if (u[q] >= 0) atomicAdd(&deg_u[u[q]], 1);
}

// merged inclusive scan per 1024-chunk for BOTH sides; nbi = item-side block count
__global__ __launch_bounds__(SCAN_B) void scan1_k(
    const int* __restrict__ deg_i, const int* __restrict__ deg_u,
    int* __restrict__ part_i, int* __restrict__ part_u,
    int* __restrict__ bsum_i, int* __restrict__ bsum_u, int nbi)
{
    __shared__ int s[SCAN_B];
    const int* deg; int* partial; int* bsum; int n, bb;
    if ((int)blockIdx.x < nbi) { deg = deg_i; partial = part_i; bsum = bsum_i; n = NITM; bb = blockIdx.x; }
    else { deg = deg_u; partial = part_u; bsum = bsum_u; n = NUSR; bb = blockIdx.x - nbi; }
    int tid = threadIdx.x;
    int i = bb * SCAN_B + tid;
    s[tid] = (i < n) ? deg[i] : 0;
    __syncthreads();
    for (int off = 1; off < SCAN_B; off <<= 1) {
        int t = (tid >= off) ? s[tid - off] : 0;
        __syncthreads();
        s[tid] += t;
        __syncthreads();
    }
    if (i < n) partial[i] = s[tid];
    if (tid == SCAN_B - 1) bsum[bb] = s[tid];
}

// merged exclusive scan of block sums: block 0 = items, block 1 = users
__global__ __launch_bounds__(128) void scan2_k(
    int* __restrict__ bsum_i, int* __restrict__ bsum_u, int nbi, int nbu)
{
    __shared__ int s[128];
    int* bsum = (blockIdx.x == 0) ? bsum_i : bsum_u;
    int nb = (blockIdx.x == 0) ? nbi : nbu;
    int tid = threadIdx.x;
    s[tid] = (tid < nb) ? bsum[tid] : 0;
    __syncthreads();
    for (int off = 1; off < 128; off <<= 1) {
        int t = (tid >= off) ? s[tid - off] : 0;
        __syncthreads();
        s[tid] += t;
        __syncthreads();
    }
    if (tid < nb) bsum[tid] = (tid == 0) ? 0 : s[tid - 1];
}

// merged rowptr + cursor init for both sides
__global__ __launch_bounds__(SCAN_B) void scan3_k(
    const int* __restrict__ deg_i, const int* __restrict__ deg_u,
    const int* __restrict__ part_i, const int* __restrict__ part_u,
    const int* __restrict__ bsum_i, const int* __restrict__ bsum_u,
    int* __restrict__ rowptr_i, int* __restrict__ rowptr_u,
    int* __restrict__ cur_i, int* __restrict__ cur_u, int nbi)
{
    const int* deg; const int* partial; const int* bsum;
    int* rowptr; int* cursor; int n, bb;
    if ((int)blockIdx.x < nbi) {
        deg = deg_i; partial = part_i; bsum = bsum_i;
        rowptr = rowptr_i; cursor = cur_i; n = NITM; bb = blockIdx.x;
    } else {
        deg = deg_u; partial = part_u; bsum = bsum_u;
        rowptr = rowptr_u; cursor = cur_u; n = NUSR; bb = blockIdx.x - nbi;
    }
    int i = bb * SCAN_B + threadIdx.x;
    if (i < n) {
        int rs = partial[i] - deg[i] + bsum[bb];
        rowptr[i] = rs;
        cursor[i] = rs;
    }
    if (i == 0) rowptr[n] = NEDG;
}

__global__ __launch_bounds__(256) void scatter_k(
    const int* __restrict__ u_idx, const int* __restrict__ i_idx,
    int* __restrict__ cur_i, int* __restrict__ cur_u,
    int* __restrict__ csr_i, int* __restrict__ csr_u)
{
    int base = (blockIdx.x * 256 + threadIdx.x) * 2;
    int u[2], it[2], p[2], r[2];
    #pragma unroll
    for (int q = 0; q < 2; q++) {
        int e = base + q;
        u[q]  = (e < NEDG) ? u_idx[e] : -1;
        it[q] = (e < NEDG) ? i_idx[e] : -1;
    }
    #pragma unroll
    for (int q = 0; q < 2; q++) if (it[q] >= 0) p[q] = atomicAdd(&cur_i[it[q]], 1);
    #pragma unroll
    for (int q = 0; q < 2; q++) if (u[q] >= 0) r[q] = atomicAdd(&cur_u[u[q]], 1);
    #pragma unroll
    for (int q = 0; q < 2; q++) if (it[q] >= 0) csr_i[p[q]] = u[q];
    #pragma unroll
    for (int q = 0; q < 2; q++) if (u[q] >= 0) csr_u[r[q]] = it[q];
}

// ========== layer-0 messages for both sides: msg = half(relu(x)+eps) =============
__global__ __launch_bounds__(256) void msg0_k(
    const float* __restrict__ xu, const float* __restrict__ xi,
    __half* __restrict__ msg_u, __half* __restrict__ msg_i)
{
    int i = blockIdx.x * 256 + threadIdx.x;
    const float* x; __half* msg; int idx;
    if (i < NUSR * 16) { x = xu; msg = msg_u; idx = i; }
    else { int j = i - NUSR * 16; if (j >= NITM * 16) return; x = xi; msg = msg_i; idx = j; }
    float4 v = ((const float4*)x)[idx];
    __half2 a = __floats2half2_rn(fmaxf(v.x, 0.f) + MSG_EPS, fmaxf(v.y, 0.f) + MSG_EPS);
    __half2 b = __floats2half2_rn(fmaxf(v.z, 0.f) + MSG_EPS, fmaxf(v.w, 0.f) + MSG_EPS);
    ((__half2*)msg)[idx * 2]     = a;
    ((__half2*)msg)[idx * 2 + 1] = b;
}

// ========== weight convert+transpose to fp16 (once per call) =====================
// W1 [6][64][128] -> W1t [6][128][64];  W2 [6][128][64] -> W2t [6][64][128]
__global__ __launch_bounds__(256) void wconv_k(
    const float* __restrict__ W1, const float* __restrict__ W2,
    __half* __restrict__ W1t, __half* __restrict__ W2t)
{
    int idx = blockIdx.x * 256 + threadIdx.x;
    if (idx >= 6 * 8192) return;
    int m = idx >> 13, rem = idx & 8191;
    {   // W1
        int k = rem >> 7, c = rem & 127;
        W1t[m * 8192 + c * 64 + k] = __float2half(W1[idx]);
    }
    {   // W2
        int k = rem >> 6, c = rem & 63;
        W2t[m * 8192 + c * 128 + k] = __float2half(W2[idx]);
    }
}

// ===== FUSED agg + GEMM1 (MFMA fp16) =============================================
// Per 64-row block: gather+online-softmax straight into LDS sA (fp16), then
// h1 = sA @ W1t + b1 (fp32 out) with BN partial stats.
// Gather phase: wave w handles rows w*16+ii*4+(lane>>4), lane&15 = feature quad.
// MFMA: A[m=lane&15][k=quad*8+j]; C/D col=lane&15, row=quad*4+reg.
#define OS1(mx,d,n,v) { float nm=fmaxf(mx,v); float sc=__expf(mx-nm); float e=__expf((v)-nm); \
                        d=d*sc+e; n=n*sc+e*(v); mx=nm; }
#define UPD(u) { float2 va=__half22float2(*(__half2*)&(u).x); \
                 float2 vb=__half22float2(*(__half2*)&(u).y); \
                 OS1(mxA,dA,nA,va.x) OS1(mxB,dB,nB,va.y) \
                 OS1(mxC,dC,nC,vb.x) OS1(mxD,dD,nD,vb.y) }

__global__ __launch_bounds__(256) void aggemm1_k(
    const __half* __restrict__ msg, const float* __restrict__ xdst,
    const int* __restrict__ rowptr, const int* __restrict__ csr,
    const __half* __restrict__ W1t,  // [128][64] f16
    const float* __restrict__ b1, float* __restrict__ h1,
    double* __restrict__ gsum, double* __restrict__ gsq, int N)
{
    __shared__ _Float16 sA[64][72];      // 9.2 KB
    __shared__ _Float16 sB[128][72];     // 18.4 KB
    __shared__ float sredS[4][128];      // 2 KB
    __shared__ float sredQ[4][128];      // 2 KB

    int t = threadIdx.x;
    int r0 = blockIdx.x * 64;
    // stage W1t: 128 rows x 8 float4
    for (int i = t; i < 1024; i += 256) {
        int row = i >> 3, c8 = i & 7;
        *(float4*)&sB[row][c8 * 8] = ((const float4*)W1t)[i];
    }

    int w = t >> 6, lane = t & 63, q = lane >> 4, ln = lane & 15;
    const uint2* mp = (const uint2*)msg;

    // gather + online softmax for this block's 64 rows, results into sA
    #pragma unroll
    for (int ii = 0; ii < 4; ii++) {
        int rr = w * 16 + ii * 4 + q;
        int r = r0 + rr;
        uint2 o = make_uint2(0u, 0u);
        if (r < N) {
            int beg = rowptr[r], end = rowptr[r + 1];
            float mxA=-1e30f,mxB=-1e30f,mxC=-1e30f,mxD=-1e30f;
            float dA=0.f,dB=0.f,dC=0.f,dD=0.f,nA=0.f,nB=0.f,nC=0.f,nD=0.f;
            int j = beg;
            for (; j + 4 <= end; j += 4) {
                int s0=csr[j], s1=csr[j+1], s2=csr[j+2], s3=csr[j+3];
                uint2 u0 = mp[(size_t)s0*16+ln];
                uint2 u1 = mp[(size_t)s1*16+ln];
                uint2 u2 = mp[(size_t)s2*16+ln];
                uint2 u3 = mp[(size_t)s3*16+ln];
                UPD(u0) UPD(u1) UPD(u2) UPD(u3)
            }
            for (; j < end; j++) {
                uint2 u = mp[(size_t)csr[j]*16+ln];
                UPD(u)
            }
            bool nz = end > beg;
            float aA = nz ? nA/dA : 0.f;
            float aB = nz ? nB/dB : 0.f;
            float aC = nz ? nC/dC : 0.f;
            float aD = nz ? nD/dD : 0.f;
            float4 xd = ((const float4*)xdst)[(size_t)r*16 + ln];
            __half2 h01 = __floats2half2_rn(aA+xd.x, aB+xd.y);
            __half2 h23 = __floats2half2_rn(aC+xd.z, aD+xd.w);
            o.x = *(unsigned int*)&h01; o.y = *(unsigned int*)&h23;
        }
        *(uint2*)&sA[rr][ln * 4] = o;
    }
    __syncthreads();

    f16x8 afr[4][2], bfr[2][2];
    #pragma unroll
    for (int rt = 0; rt < 4; rt++)
        #pragma unroll
        for (int ks = 0; ks < 2; ks++)
            afr[rt][ks] = *(const f16x8*)&sA[rt * 16 + ln][ks * 32 + q * 8];
    #pragma unroll
    for (int ct = 0; ct < 2; ct++)
        #pragma unroll
        for (int ks = 0; ks < 2; ks++)
            bfr[ct][ks] = *(const f16x8*)&sB[w * 32 + ct * 16 + ln][ks * 32 + q * 8];

    f32x4 acc[4][2];
    #pragma unroll
    for (int rt = 0; rt < 4; rt++)
        #pragma unroll
        for (int ct = 0; ct < 2; ct++)
            acc[rt][ct] = (f32x4){0.f, 0.f, 0.f, 0.f};

    #pragma unroll
    for (int rt = 0; rt < 4; rt++)
        #pragma unroll
        for (int ct = 0; ct < 2; ct++) {
            acc[rt][ct] = __builtin_amdgcn_mfma_f32_16x16x32_f16(
                afr[rt][0], bfr[ct][0], acc[rt][ct], 0, 0, 0);
            acc[rt][ct] = __builtin_amdgcn_mfma_f32_16x16x32_f16(
                afr[rt][1], bfr[ct][1], acc[rt][ct], 0, 0, 0);
        }

    float b1c0 = b1[w * 32 + ln];
    float b1c1 = b1[w * 32 + 16 + ln];
    float ps0 = 0.f, pq0 = 0.f, ps1 = 0.f, pq1 = 0.f;
    #pragma unroll
    for (int rt = 0; rt < 4; rt++) {
        #pragma unroll
        for (int i = 0; i < 4; i++) {
            int r = r0 + rt * 16 + q * 4 + i;
            if (r < N) {
                float h0 = acc[rt][0][i] + b1c0;
                float h1v = acc[rt][1][i] + b1c1;
                h1[(size_t)r * DD2 + w * 32 + ln] = h0;
                h1[(size_t)r * DD2 + w * 32 + 16 + ln] = h1v;
                ps0 += h0; pq0 += h0 * h0;
                ps1 += h1v; pq1 += h1v * h1v;
            }
        }
    }
    sredS[q][w * 32 + ln] = ps0;  sredS[q][w * 32 + 16 + ln] = ps1;
    sredQ[q][w * 32 + ln] = pq0;  sredQ[q][w * 32 + 16 + ln] = pq1;
    __syncthreads();
    if (t < 128) {
        float s = 0.f, qq = 0.f;
        #pragma unroll
        for (int k = 0; k < 4; k++) { s += sredS[k][t]; qq += sredQ[k][t]; }
        atomicAdd(&gsum[t], (double)s);
        atomicAdd(&gsq[t],  (double)qq);
    }
}

// ===== GEMM2 (MFMA fp16): xnew = relu(relu(bn(h1)) @ W2 + b2) + msg epilogue =====
__global__ __launch_bounds__(256) void gemm2_k(
    const float* __restrict__ h1,
    const double* __restrict__ gsum, const double* __restrict__ gsq,
    const float* __restrict__ gamma, const float* __restrict__ beta,
    const __half* __restrict__ W2t,  // [64][128] f16 (n-major)
    const float* __restrict__ b2,
    float* __restrict__ xnew, __half* __restrict__ msgout, int N)
{
    __shared__ _Float16 sA[64][136];    // 17.4 KB
    __shared__ _Float16 sB[64][136];    // 17.4 KB
    __shared__ float2 sss[DD2];         // 1 KB

    int t = threadIdx.x;
    if (t < 128) {
        double mean = gsum[t] / (double)N;
        double var  = gsq[t] / (double)N - mean * mean;
        float inv = (float)(1.0 / sqrt(var + (double)BN_EPS));
        float sc = gamma[t] * inv;
        sss[t] = make_float2(sc, beta[t] - (float)mean * sc);
    }
    // stage W2t: 64 rows x 16 float4
    for (int i = t; i < 1024; i += 256) {
        int row = i >> 4, c8 = i & 15;
        *(float4*)&sB[row][c8 * 8] = ((const float4*)W2t)[i];
    }
    __syncthreads();

    int r0 = blockIdx.x * 64;
    // stage h1 with BN + relu -> fp16: 64 rows x 32 float4
    for (int i = t; i < 2048; i += 256) {
        int rr = i >> 5, c4 = i & 31;
        int r = r0 + rr;
        float4 v = make_float4(0.f, 0.f, 0.f, 0.f);
        if (r < N) {
            v = ((const float4*)h1)[(size_t)r * 32 + c4];
            float2 s0 = sss[c4 * 4], s1 = sss[c4 * 4 + 1];
            float2 s2 = sss[c4 * 4 + 2], s3 = sss[c4 * 4 + 3];
            v.x = fmaxf(fmaf(v.x, s0.x, s0.y), 0.f);
            v.y = fmaxf(fmaf(v.y, s1.x, s1.y), 0.f);
            v.z = fmaxf(fmaf(v.z, s2.x, s2.y), 0.f);
            v.w = fmaxf(fmaf(v.w, s3.x, s3.y), 0.f);
        }
        __half2 a = __floats2half2_rn(v.x, v.y);
        __half2 b = __floats2half2_rn(v.z, v.w);
        uint2 o; o.x = *(unsigned int*)&a; o.y = *(unsigned int*)&b;
        *(uint2*)&sA[rr][c4 * 4] = o;
    }
    __syncthreads();

    int w = t >> 6, lane = t & 63, q = lane >> 4, ln = lane & 15;
    f32x4 acc[4];
    #pragma unroll
    for (int rt = 0; rt < 4; rt++) acc[rt] = (f32x4){0.f, 0.f, 0.f, 0.f};

    #pragma unroll
    for (int ks = 0; ks < 4; ks++) {
        f16x8 bf = *(const f16x8*)&sB[w * 16 + ln][ks * 32 + q * 8];
        #pragma unroll
        for (int rt = 0; rt < 4; rt++) {
            f16x8 af = *(const f16x8*)&sA[rt * 16 + ln][ks * 32 + q * 8];
            acc[rt] = __builtin_amdgcn_mfma_f32_16x16x32_f16(af, bf, acc[rt], 0, 0, 0);
        }
    }

    int c = w * 16 + ln;
    float bb = b2[c];
    #pragma unroll
    for (int rt = 0; rt < 4; rt++) {
        #pragma unroll
        for (int i = 0; i < 4; i++) {
            int r = r0 + rt * 16 + q * 4 + i;
            if (r < N) {
                float o = fmaxf(acc[rt][i] + bb, 0.f);
                xnew[(size_t)r * DD + c] = o;
                msgout[(size_t)r * DD + c] = __float2half(o + MSG_EPS);
            }
        }
    }
}

// ================= decoder ========================================================
__global__ __launch_bounds__(256) void decode_k(
    const float* __restrict__ xu, const float* __restrict__ xi,
    const int* __restrict__ pu, const int* __restrict__ pi,
    float* __restrict__ out)
{
    int idx = blockIdx.x * 256 + threadIdx.x;
    int b = idx >> 4, lane = idx & 15;
    if (b >= NPRED) return;
    int u = pu[b], it = pi[b];
    float4 a = ((const float4*)(xu + (size_t)u * DD))[lane];
    float4 c = ((const float4*)(xi + (size_t)it * DD))[lane];
    float s = a.x * c.x + a.y * c.y + a.z * c.z + a.w * c.w;
    #pragma unroll
    for (int off = 8; off; off >>= 1) s += __shfl_down(s, off, 16);
    if (lane == 0) out[b] = s;
}

// ================= host-side conv driver ==========================================
static void run_conv(const __half* msg_src, const float* xdst,
                     const int* rowptr, const int* csr, int Ndst,
                     const __half* W1tp, const float* b1p,
                     const float* gp, const float* bp,
                     const __half* W2tp, const float* b2p,
                     float* h1, double* gs, double* gq,
                     float* xnew, __half* msg_out, hipStream_t stream)
{
    aggemm1_k<<<(Ndst + 63) / 64, 256, 0, stream>>>(msg_src, xdst, rowptr, csr,
                                                    W1tp, b1p, h1, gs, gq, Ndst);
    gemm2_k<<<(Ndst + 63) / 64, 256, 0, stream>>>(h1, gs, gq, gp, bp, W2tp, b2p,
                                                  xnew, msg_out, Ndst);
}

extern "C" void kernel_launch(void* const* d_in, const int* in_sizes, int n_in,
                              void* d_out, int out_size, void* d_ws, size_t ws_size,
                              hipStream_t stream)
{
    const float* x_user = (const float*)d_in[0];
    const float* x_item = (const float*)d_in[1];
    const float* W1    = (const float*)d_in[2];   // [3][2][64][128]
    const float* b1    = (const float*)d_in[3];
    const float* gamma = (const float*)d_in[4];
    const float* beta  = (const float*)d_in[5];
    const float* W2    = (const float*)d_in[6];   // [3][2][128][64]
    const float* b2    = (const float*)d_in[7];
    const int* edge = (const int*)d_in[8];        // [2][E]
    const int* pred = (const int*)d_in[9];        // [2][B]
    float* out = (float*)d_out;

    const int* u_idx = edge;
    const int* i_idx = edge + NEDG;

    // ---- workspace bump allocator (256B aligned chunks) ----
    char* p = (char*)d_ws;
    #define ALLOC(ptr, type, count) \
        type* ptr = (type*)p; p += (((size_t)(count) * sizeof(type)) + 255) & ~(size_t)255;

    // deg_i, deg_u, gsumAll contiguous -> single memset covers all three
    ALLOC(deg_i, int, NITM)
    ALLOC(deg_u, int, NUSR)
    ALLOC(gsumAll, double, 12 * 256)             // 6 convs x (gsum[128]|gsq[128])
    size_t zero_span = (char*)p - (char*)deg_i;
    ALLOC(part_i, int, NITM)
    ALLOC(part_u, int, NUSR)
    ALLOC(bsum_i, int, 128)
    ALLOC(bsum_u, int, 128)
    ALLOC(rowptr_i, int, NITM + 1)
    ALLOC(rowptr_u, int, NUSR + 1)
    ALLOC(cur_i, int, NITM)
    ALLOC(cur_u, int, NUSR)
    ALLOC(csr_i, int, NEDG)          // per-item incident users
    ALLOC(csr_u, int, NEDG)          // per-user incident items
    ALLOC(h1, float, (size_t)NUSR * DD2)
    ALLOC(W1t, __half, 6 * 8192)
    ALLOC(W2t, __half, 6 * 8192)
    ALLOC(xu0, float, (size_t)NUSR * DD)
    ALLOC(xu1, float, (size_t)NUSR * DD)
    ALLOC(xi0, float, (size_t)NITM * DD)
    ALLOC(xi1, float, (size_t)NITM * DD)
    ALLOC(msg_u, __half, (size_t)NUSR * DD)
    ALLOC(msg_i0, __half, (size_t)NITM * DD)
    ALLOC(msg_i1, __half, (size_t)NITM * DD)
    #undef ALLOC
    float* xu_buf[2] = {xu0, xu1};
    float* xi_buf[2] = {xi0, xi1};

    // ---- CSR build + converts (once; reused by all 3 layers) ----
    hipMemsetAsync(deg_i, 0, zero_span, stream);
    int eb2 = (NEDG / 2 + 255) / 256;
    count_k<<<eb2, 256, 0, stream>>>(u_idx, i_idx, deg_u, deg_i);

    int nbi = (NITM + SCAN_B - 1) / SCAN_B;   // 49
    int nbu = (NUSR + SCAN_B - 1) / SCAN_B;   // 98
    scan1_k<<<nbi + nbu, SCAN_B, 0, stream>>>(deg_i, deg_u, part_i, part_u,
                                              bsum_i, bsum_u, nbi);
    scan2_k<<<2, 128, 0, stream>>>(bsum_i, bsum_u, nbi, nbu);
    scan3_k<<<nbi + nbu, SCAN_B, 0, stream>>>(deg_i, deg_u, part_i, part_u,
                                              bsum_i, bsum_u, rowptr_i, rowptr_u,
                                              cur_i, cur_u, nbi);
    scatter_k<<<eb2, 256, 0, stream>>>(u_idx, i_idx, cur_i, cur_u, csr_i, csr_u);

    wconv_k<<<(6 * 8192 + 255) / 256, 256, 0, stream>>>(W1, W2, W1t, W2t);
    msg0_k<<<((NUSR + NITM) * 16 + 255) / 256, 256, 0, stream>>>(x_user, x_item,
                                                                 msg_u, msg_i0);

    // ---- 3 layers x 2 convs ----
    const float* cu = x_user;
    const float* ci = x_item;
    __half* msgi = msg_i0;
    __half* msgi_alt = msg_i1;
    for (int l = 0; l < 3; l++) {
        int o0 = l * 2 + 0;   // user->item conv params
        int o1 = l * 2 + 1;   // item->user conv params
        float* ni = xi_buf[l & 1];
        float* nu = xu_buf[l & 1];
        // conv0 (src=user msgs, dst=item); writes new item msgs to alt buffer
        run_conv(msg_u, ci, rowptr_i, csr_i, NITM,
                 W1t + (size_t)o0 * 8192, b1 + (size_t)o0 * DD2,
                 gamma + (size_t)o0 * DD2, beta + (size_t)o0 * DD2,
                 W2t + (size_t)o0 * 8192, b2 + (size_t)o0 * DD,
                 h1, gsumAll + o0 * 256, gsumAll + o0 * 256 + 128,
                 ni, msgi_alt, stream);
        // conv1 (src=item msgs OLD, dst=user); overwrites msg_u (already consumed)
        run_conv(msgi, cu, rowptr_u, csr_u, NUSR,
                 W1t + (size_t)o1 * 8192, b1 + (size_t)o1 * DD2,
                 gamma + (size_t)o1 * DD2, beta + (size_t)o1 * DD2,
                 W2t + (size_t)o1 * 8192, b2 + (size_t)o1 * DD,
                 h1, gsumAll + o1 * 256, gsumAll + o1 * 256 + 128,
                 nu, msg_u, stream);
        cu = nu; ci = ni;
        __half* tmp = msgi; msgi = msgi_alt; msgi_alt = tmp;
    }

    decode_k<<<(NPRED * 16) / 256, 256, 0, stream>>>(cu, ci, pred, pred + NPRED, out);
}

// Round 9
// 730.880 us; speedup vs baseline: 6.0797x; 1.1831x over previous
//
#include <hip/hip_runtime.h>
#include <hip/hip_fp16.h>

#define NUSR 100000
#define NITM 50000
#define NEDG 1000000
#define NPRED 250000
#define DD 64
#define DD2 128
#define MSG_EPS 1e-7f
#define BN_EPS 1e-5f
#define SCAN_B 1024

typedef _Float16 f16x8 __attribute__((ext_vector_type(8)));
typedef float f32x4 __attribute__((ext_vector_type(4)));

// ================= CSR build (once per call; edges are layer-invariant) ==========

__global__ __launch_bounds__(256) void count_k(
    const int* __restrict__ u_idx, const int* __restrict__ i_idx,
    int* __restrict__ deg_u, int* __restrict__ deg_i)
{
    int base = (blockIdx.x * 256 + threadIdx.x) * 2;
    int u[2], it[2];
    #pragma unroll
    for (int q = 0; q < 2; q++) {
        int e = base + q;
        u[q]  = (e < NEDG) ? u_idx[e] : -1;
        it[q] = (e < NEDG) ? i_idx[e] : -1;
    }
    #pragma unroll
    for (int q = 0; q < 2; q++) if (it[q] >= 0) atomicAdd(&deg_i[it[q]], 1);
    #pragma unroll
    for (int q = 0; q < 2; q++) if (u[q] >= 0) atomicAdd(&deg_u[u[q]], 1);
}

// merged inclusive scan per 1024-chunk for BOTH sides; nbi = item-side block count
__global__ __launch_bounds__(SCAN_B) void scan1_k(
    const int* __restrict__ deg_i, const int* __restrict__ deg_u,
    int* __restrict__ part_i, int* __restrict__ part_u,
    int* __restrict__ bsum_i, int* __restrict__ bsum_u, int nbi)
{
    __shared__ int s[SCAN_B];
    const int* deg; int* partial; int* bsum; int n, bb;
    if ((int)blockIdx.x < nbi) { deg = deg_i; partial = part_i; bsum = bsum_i; n = NITM; bb = blockIdx.x; }
    else { deg = deg_u; partial = part_u; bsum = bsum_u; n = NUSR; bb = blockIdx.x - nbi; }
    int tid = threadIdx.x;
    int i = bb * SCAN_B + tid;
    s[tid] = (i < n) ? deg[i] : 0;
    __syncthreads();
    for (int off = 1; off < SCAN_B; off <<= 1) {
        int t = (tid >= off) ? s[tid - off] : 0;
        __syncthreads();
        s[tid] += t;
        __syncthreads();
    }
    if (i < n) partial[i] = s[tid];
    if (tid == SCAN_B - 1) bsum[bb] = s[tid];
}

__global__ __launch_bounds__(128) void scan2_k(
    int* __restrict__ bsum_i, int* __restrict__ bsum_u, int nbi, int nbu)
{
    __shared__ int s[128];
    int* bsum = (blockIdx.x == 0) ? bsum_i : bsum_u;
    int nb = (blockIdx.x == 0) ? nbi : nbu;
    int tid = threadIdx.x;
    s[tid] = (tid < nb) ? bsum[tid] : 0;
    __syncthreads();
    for (int off = 1; off < 128; off <<= 1) {
        int t = (tid >= off) ? s[tid - off] : 0;
        __syncthreads();
        s[tid] += t;
        __syncthreads();
    }
    if (tid < nb) bsum[tid] = (tid == 0) ? 0 : s[tid - 1];
}

__global__ __launch_bounds__(SCAN_B) void scan3_k(
    const int* __restrict__ deg_i, const int* __restrict__ deg_u,
    const int* __restrict__ part_i, const int* __restrict__ part_u,
    const int* __restrict__ bsum_i, const int* __restrict__ bsum_u,
    int* __restrict__ rowptr_i, int* __restrict__ rowptr_u,
    int* __restrict__ cur_i, int* __restrict__ cur_u, int nbi)
{
    const int* deg; const int* partial; const int* bsum;
    int* rowptr; int* cursor; int n, bb;
    if ((int)blockIdx.x < nbi) {
        deg = deg_i; partial = part_i; bsum = bsum_i;
        rowptr = rowptr_i; cursor = cur_i; n = NITM; bb = blockIdx.x;
    } else {
        deg = deg_u; partial = part_u; bsum = bsum_u;
        rowptr = rowptr_u; cursor = cur_u; n = NUSR; bb = blockIdx.x - nbi;
    }
    int i = bb * SCAN_B + threadIdx.x;
    if (i < n) {
        int rs = partial[i] - deg[i] + bsum[bb];
        rowptr[i] = rs;
        cursor[i] = rs;
    }
    if (i == 0) rowptr[n] = NEDG;
}

__global__ __launch_bounds__(256) void scatter_k(
    const int* __restrict__ u_idx, const int* __restrict__ i_idx,
    int* __restrict__ cur_i, int* __restrict__ cur_u,
    int* __restrict__ csr_i, int* __restrict__ csr_u)
{
    int base = (blockIdx.x * 256 + threadIdx.x) * 2;
    int u[2], it[2], p[2], r[2];
    #pragma unroll
    for (int q = 0; q < 2; q++) {
        int e = base + q;
        u[q]  = (e < NEDG) ? u_idx[e] : -1;
        it[q] = (e < NEDG) ? i_idx[e] : -1;
    }
    #pragma unroll
    for (int q = 0; q < 2; q++) if (it[q] >= 0) p[q] = atomicAdd(&cur_i[it[q]], 1);
    #pragma unroll
    for (int q = 0; q < 2; q++) if (u[q] >= 0) r[q] = atomicAdd(&cur_u[u[q]], 1);
    #pragma unroll
    for (int q = 0; q < 2; q++) if (it[q] >= 0) csr_i[p[q]] = u[q];
    #pragma unroll
    for (int q = 0; q < 2; q++) if (u[q] >= 0) csr_u[r[q]] = it[q];
}

// ========== layer-0 messages for both sides: msg = half(relu(x)+eps) =============
__global__ __launch_bounds__(256) void msg0_k(
    const float* __restrict__ xu, const float* __restrict__ xi,
    __half* __restrict__ msg_u, __half* __restrict__ msg_i)
{
    int i = blockIdx.x * 256 + threadIdx.x;
    const float* x; __half* msg; int idx;
    if (i < NUSR * 16) { x = xu; msg = msg_u; idx = i; }
    else { int j = i - NUSR * 16; if (j >= NITM * 16) return; x = xi; msg = msg_i; idx = j; }
    float4 v = ((const float4*)x)[idx];
    __half2 a = __floats2half2_rn(fmaxf(v.x, 0.f) + MSG_EPS, fmaxf(v.y, 0.f) + MSG_EPS);
    __half2 b = __floats2half2_rn(fmaxf(v.z, 0.f) + MSG_EPS, fmaxf(v.w, 0.f) + MSG_EPS);
    ((__half2*)msg)[idx * 2]     = a;
    ((__half2*)msg)[idx * 2 + 1] = b;
}

// ========== weight convert+transpose to fp16 (once per call) =====================
__global__ __launch_bounds__(256) void wconv_k(
    const float* __restrict__ W1, const float* __restrict__ W2,
    __half* __restrict__ W1t, __half* __restrict__ W2t)
{
    int idx = blockIdx.x * 256 + threadIdx.x;
    if (idx >= 6 * 8192) return;
    int m = idx >> 13, rem = idx & 8191;
    {   // W1 [64][128] -> [128][64]
        int k = rem >> 7, c = rem & 127;
        W1t[m * 8192 + c * 64 + k] = __float2half(W1[idx]);
    }
    {   // W2 [128][64] -> [64][128]
        int k = rem >> 6, c = rem & 63;
        W2t[m * 8192 + c * 128 + k] = __float2half(W2[idx]);
    }
}

// ===== FUSED (item-conv + user-conv) agg + GEMM1 (MFMA fp16) =====================
// softmax WITHOUT max-subtraction (mathematically identical; m in [eps, ~6] so
// exp() is safe in fp32): den = sum exp(m), num = sum exp(m)*m, agg = num/den.
#define UPD(u) { float2 va=__half22float2(*(__half2*)&(u).x); \
                 float2 vb=__half22float2(*(__half2*)&(u).y); \
                 float eA=__expf(va.x), eB=__expf(va.y); \
                 float eC=__expf(vb.x), eD=__expf(vb.y); \
                 dA+=eA; nA=fmaf(eA,va.x,nA); dB+=eB; nB=fmaf(eB,va.y,nB); \
                 dC+=eC; nC=fmaf(eC,vb.x,nC); dD+=eD; nD=fmaf(eD,vb.y,nD); }

__global__ __launch_bounds__(256) void aggemm1f_k(
    const __half* __restrict__ msg_i_src, const __half* __restrict__ msg_u_src,
    const float* __restrict__ xi_cur, const float* __restrict__ xu_cur,
    const int* __restrict__ rowptr_i, const int* __restrict__ rowptr_u,
    const int* __restrict__ csr_i, const int* __restrict__ csr_u,
    const __half* __restrict__ W1t_l,   // layer base: [2][128][64] f16
    const float* __restrict__ b1_l,     // [2][128]
    float* __restrict__ h1_i, float* __restrict__ h1_u,
    double* __restrict__ gs_l,          // [2][256] (gsum|gsq per conv)
    int gI)
{
    __shared__ _Float16 sA[64][72];      // 9.2 KB
    __shared__ _Float16 sB[128][72];     // 18.4 KB
    __shared__ float sredS[4][128];      // 2 KB
    __shared__ float sredQ[4][128];      // 2 KB

    int side = ((int)blockIdx.x < gI) ? 0 : 1;
    int bb = side ? (blockIdx.x - gI) : blockIdx.x;
    // side 0: dst=item (gather user msgs); side 1: dst=user (gather item msgs)
    const __half* msg = side ? msg_i_src : msg_u_src;
    const float* xdst = side ? xu_cur : xi_cur;
    const int* rowptr = side ? rowptr_u : rowptr_i;
    const int* csr    = side ? csr_u : csr_i;
    const __half* W1t = W1t_l + (size_t)side * 8192;
    const float* b1   = b1_l + side * DD2;
    float* h1         = side ? h1_u : h1_i;
    double* gsum      = gs_l + side * 256;
    double* gsq       = gsum + 128;
    int N             = side ? NUSR : NITM;

    int t = threadIdx.x;
    int r0 = bb * 64;
    for (int i = t; i < 1024; i += 256) {
        int row = i >> 3, c8 = i & 7;
        *(float4*)&sB[row][c8 * 8] = ((const float4*)W1t)[i];
    }

    int w = t >> 6, lane = t & 63, q = lane >> 4, ln = lane & 15;
    const uint2* mp = (const uint2*)msg;

    // gather + softmax-agg for this block's 64 rows, results into sA
    #pragma unroll
    for (int ii = 0; ii < 4; ii++) {
        int rr = w * 16 + ii * 4 + q;
        int r = r0 + rr;
        uint2 o = make_uint2(0u, 0u);
        if (r < N) {
            int beg = rowptr[r], end = rowptr[r + 1];
            float dA=0.f,dB=0.f,dC=0.f,dD=0.f,nA=0.f,nB=0.f,nC=0.f,nD=0.f;
            int j = beg;
            for (; j + 4 <= end; j += 4) {
                int s0=csr[j], s1=csr[j+1], s2=csr[j+2], s3=csr[j+3];
                uint2 u0 = mp[(size_t)s0*16+ln];
                uint2 u1 = mp[(size_t)s1*16+ln];
                uint2 u2 = mp[(size_t)s2*16+ln];
                uint2 u3 = mp[(size_t)s3*16+ln];
                UPD(u0) UPD(u1) UPD(u2) UPD(u3)
            }
            for (; j < end; j++) {
                uint2 u = mp[(size_t)csr[j]*16+ln];
                UPD(u)
            }
            bool nz = end > beg;
            float aA = nz ? nA/dA : 0.f;
            float aB = nz ? nB/dB : 0.f;
            float aC = nz ? nC/dC : 0.f;
            float aD = nz ? nD/dD : 0.f;
            float4 xd = ((const float4*)xdst)[(size_t)r*16 + ln];
            __half2 h01 = __floats2half2_rn(aA+xd.x, aB+xd.y);
            __half2 h23 = __floats2half2_rn(aC+xd.z, aD+xd.w);
            o.x = *(unsigned int*)&h01; o.y = *(unsigned int*)&h23;
        }
        *(uint2*)&sA[rr][ln * 4] = o;
    }
    __syncthreads();

    f16x8 afr[4][2], bfr[2][2];
    #pragma unroll
    for (int rt = 0; rt < 4; rt++)
        #pragma unroll
        for (int ks = 0; ks < 2; ks++)
            afr[rt][ks] = *(const f16x8*)&sA[rt * 16 + ln][ks * 32 + q * 8];
    #pragma unroll
    for (int ct = 0; ct < 2; ct++)
        #pragma unroll
        for (int ks = 0; ks < 2; ks++)
            bfr[ct][ks] = *(const f16x8*)&sB[w * 32 + ct * 16 + ln][ks * 32 + q * 8];

    f32x4 acc[4][2];
    #pragma unroll
    for (int rt = 0; rt < 4; rt++)
        #pragma unroll
        for (int ct = 0; ct < 2; ct++)
            acc[rt][ct] = (f32x4){0.f, 0.f, 0.f, 0.f};

    #pragma unroll
    for (int rt = 0; rt < 4; rt++)
        #pragma unroll
        for (int ct = 0; ct < 2; ct++) {
            acc[rt][ct] = __builtin_amdgcn_mfma_f32_16x16x32_f16(
                afr[rt][0], bfr[ct][0], acc[rt][ct], 0, 0, 0);
            acc[rt][ct] = __builtin_amdgcn_mfma_f32_16x16x32_f16(
                afr[rt][1], bfr[ct][1], acc[rt][ct], 0, 0, 0);
        }

    float b1c0 = b1[w * 32 + ln];
    float b1c1 = b1[w * 32 + 16 + ln];
    float ps0 = 0.f, pq0 = 0.f, ps1 = 0.f, pq1 = 0.f;
    #pragma unroll
    for (int rt = 0; rt < 4; rt++) {
        #pragma unroll
        for (int i = 0; i < 4; i++) {
            int r = r0 + rt * 16 + q * 4 + i;
            if (r < N) {
                float h0 = acc[rt][0][i] + b1c0;
                float h1v = acc[rt][1][i] + b1c1;
                h1[(size_t)r * DD2 + w * 32 + ln] = h0;
                h1[(size_t)r * DD2 + w * 32 + 16 + ln] = h1v;
                ps0 += h0; pq0 += h0 * h0;
                ps1 += h1v; pq1 += h1v * h1v;
            }
        }
    }
    sredS[q][w * 32 + ln] = ps0;  sredS[q][w * 32 + 16 + ln] = ps1;
    sredQ[q][w * 32 + ln] = pq0;  sredQ[q][w * 32 + 16 + ln] = pq1;
    __syncthreads();
    if (t < 128) {
        float s = 0.f, qq = 0.f;
        #pragma unroll
        for (int k = 0; k < 4; k++) { s += sredS[k][t]; qq += sredQ[k][t]; }
        atomicAdd(&gsum[t], (double)s);
        atomicAdd(&gsq[t],  (double)qq);
    }
}

// ===== FUSED GEMM2 (both convs): xnew = relu(relu(bn(h1)) @ W2 + b2) + msgs ======
__global__ __launch_bounds__(256) void gemm2f_k(
    const float* __restrict__ h1_i, const float* __restrict__ h1_u,
    const double* __restrict__ gs_l,
    const float* __restrict__ gamma_l, const float* __restrict__ beta_l,
    const __half* __restrict__ W2t_l, const float* __restrict__ b2_l,
    float* __restrict__ xi_new, float* __restrict__ xu_new,
    __half* __restrict__ msgi_out, __half* __restrict__ msgu_out, int gI)
{
    __shared__ _Float16 sA[64][136];    // 17.4 KB
    __shared__ _Float16 sB[64][136];    // 17.4 KB
    __shared__ float2 sss[DD2];         // 1 KB

    int side = ((int)blockIdx.x < gI) ? 0 : 1;
    int bb = side ? (blockIdx.x - gI) : blockIdx.x;
    const float* h1   = side ? h1_u : h1_i;
    const double* gsum = gs_l + side * 256;
    const double* gsq  = gsum + 128;
    const float* gamma = gamma_l + side * DD2;
    const float* beta  = beta_l + side * DD2;
    const __half* W2t  = W2t_l + (size_t)side * 8192;
    const float* b2    = b2_l + side * DD;
    float* xnew        = side ? xu_new : xi_new;
    __half* msgout     = side ? msgu_out : msgi_out;
    int N              = side ? NUSR : NITM;

    int t = threadIdx.x;
    if (t < 128) {
        double mean = gsum[t] / (double)N;
        double var  = gsq[t] / (double)N - mean * mean;
        float inv = (float)(1.0 / sqrt(var + (double)BN_EPS));
        float sc = gamma[t] * inv;
        sss[t] = make_float2(sc, beta[t] - (float)mean * sc);
    }
    for (int i = t; i < 1024; i += 256) {
        int row = i >> 4, c8 = i & 15;
        *(float4*)&sB[row][c8 * 8] = ((const float4*)W2t)[i];
    }
    __syncthreads();

    int r0 = bb * 64;
    for (int i = t; i < 2048; i += 256) {
        int rr = i >> 5, c4 = i & 31;
        int r = r0 + rr;
        float4 v = make_float4(0.f, 0.f, 0.f, 0.f);
        if (r < N) {
            v = ((const float4*)h1)[(size_t)r * 32 + c4];
            float2 s0 = sss[c4 * 4], s1 = sss[c4 * 4 + 1];
            float2 s2 = sss[c4 * 4 + 2], s3 = sss[c4 * 4 + 3];
            v.x = fmaxf(fmaf(v.x, s0.x, s0.y), 0.f);
            v.y = fmaxf(fmaf(v.y, s1.x, s1.y), 0.f);
            v.z = fmaxf(fmaf(v.z, s2.x, s2.y), 0.f);
            v.w = fmaxf(fmaf(v.w, s3.x, s3.y), 0.f);
        }
        __half2 a = __floats2half2_rn(v.x, v.y);
        __half2 b = __floats2half2_rn(v.z, v.w);
        uint2 o; o.x = *(unsigned int*)&a; o.y = *(unsigned int*)&b;
        *(uint2*)&sA[rr][c4 * 4] = o;
    }
    __syncthreads();

    int w = t >> 6, lane = t & 63, q = lane >> 4, ln = lane & 15;
    f32x4 acc[4];
    #pragma unroll
    for (int rt = 0; rt < 4; rt++) acc[rt] = (f32x4){0.f, 0.f, 0.f, 0.f};

    #pragma unroll
    for (int ks = 0; ks < 4; ks++) {
        f16x8 bf = *(const f16x8*)&sB[w * 16 + ln][ks * 32 + q * 8];
        #pragma unroll
        for (int rt = 0; rt < 4; rt++) {
            f16x8 af = *(const f16x8*)&sA[rt * 16 + ln][ks * 32 + q * 8];
            acc[rt] = __builtin_amdgcn_mfma_f32_16x16x32_f16(af, bf, acc[rt], 0, 0, 0);
        }
    }

    int c = w * 16 + ln;
    float bb2 = b2[c];
    #pragma unroll
    for (int rt = 0; rt < 4; rt++) {
        #pragma unroll
        for (int i = 0; i < 4; i++) {
            int r = r0 + rt * 16 + q * 4 + i;
            if (r < N) {
                float o = fmaxf(acc[rt][i] + bb2, 0.f);
                xnew[(size_t)r * DD + c] = o;
                msgout[(size_t)r * DD + c] = __float2half(o + MSG_EPS);
            }
        }
    }
}

// ================= decoder ========================================================
__global__ __launch_bounds__(256) void decode_k(
    const float* __restrict__ xu, const float* __restrict__ xi,
    const int* __restrict__ pu, const int* __restrict__ pi,
    float* __restrict__ out)
{
    int idx = blockIdx.x * 256 + threadIdx.x;
    int b = idx >> 4, lane = idx & 15;
    if (b >= NPRED) return;
    int u = pu[b], it = pi[b];
    float4 a = ((const float4*)(xu + (size_t)u * DD))[lane];
    float4 c = ((const float4*)(xi + (size_t)it * DD))[lane];
    float s = a.x * c.x + a.y * c.y + a.z * c.z + a.w * c.w;
    #pragma unroll
    for (int off = 8; off; off >>= 1) s += __shfl_down(s, off, 16);
    if (lane == 0) out[b] = s;
}

extern "C" void kernel_launch(void* const* d_in, const int* in_sizes, int n_in,
                              void* d_out, int out_size, void* d_ws, size_t ws_size,
                              hipStream_t stream)
{
    const float* x_user = (const float*)d_in[0];
    const float* x_item = (const float*)d_in[1];
    const float* W1    = (const float*)d_in[2];   // [3][2][64][128]
    const float* b1    = (const float*)d_in[3];
    const float* gamma = (const float*)d_in[4];
    const float* beta  = (const float*)d_in[5];
    const float* W2    = (const float*)d_in[6];   // [3][2][128][64]
    const float* b2    = (const float*)d_in[7];
    const int* edge = (const int*)d_in[8];        // [2][E]
    const int* pred = (const int*)d_in[9];        // [2][B]
    float* out = (float*)d_out;

    const int* u_idx = edge;
    const int* i_idx = edge + NEDG;

    // ---- workspace bump allocator (256B aligned chunks) ----
    char* p = (char*)d_ws;
    #define ALLOC(ptr, type, count) \
        type* ptr = (type*)p; p += (((size_t)(count) * sizeof(type)) + 255) & ~(size_t)255;

    ALLOC(deg_i, int, NITM)
    ALLOC(deg_u, int, NUSR)
    ALLOC(gsumAll, double, 12 * 256)             // 6 convs x (gsum[128]|gsq[128])
    size_t zero_span = (char*)p - (char*)deg_i;
    ALLOC(part_i, int, NITM)
    ALLOC(part_u, int, NUSR)
    ALLOC(bsum_i, int, 128)
    ALLOC(bsum_u, int, 128)
    ALLOC(rowptr_i, int, NITM + 1)
    ALLOC(rowptr_u, int, NUSR + 1)
    ALLOC(cur_i, int, NITM)
    ALLOC(cur_u, int, NUSR)
    ALLOC(csr_i, int, NEDG)
    ALLOC(csr_u, int, NEDG)
    ALLOC(h1_i, float, (size_t)NITM * DD2)
    ALLOC(h1_u, float, (size_t)NUSR * DD2)
    ALLOC(W1t, __half, 6 * 8192)
    ALLOC(W2t, __half, 6 * 8192)
    ALLOC(xu0, float, (size_t)NUSR * DD)
    ALLOC(xu1, float, (size_t)NUSR * DD)
    ALLOC(xi0, float, (size_t)NITM * DD)
    ALLOC(xi1, float, (size_t)NITM * DD)
    ALLOC(msg_u, __half, (size_t)NUSR * DD)
    ALLOC(msg_i0, __half, (size_t)NITM * DD)
    ALLOC(msg_i1, __half, (size_t)NITM * DD)
    #undef ALLOC
    float* xu_buf[2] = {xu0, xu1};
    float* xi_buf[2] = {xi0, xi1};

    // ---- CSR build + converts (once; reused by all 3 layers) ----
    hipMemsetAsync(deg_i, 0, zero_span, stream);
    int eb2 = (NEDG / 2 + 255) / 256;
    count_k<<<eb2, 256, 0, stream>>>(u_idx, i_idx, deg_u, deg_i);

    int nbi = (NITM + SCAN_B - 1) / SCAN_B;   // 49
    int nbu = (NUSR + SCAN_B - 1) / SCAN_B;   // 98
    scan1_k<<<nbi + nbu, SCAN_B, 0, stream>>>(deg_i, deg_u, part_i, part_u,
                                              bsum_i, bsum_u, nbi);
    scan2_k<<<2, 128, 0, stream>>>(bsum_i, bsum_u, nbi, nbu);
    scan3_k<<<nbi + nbu, SCAN_B, 0, stream>>>(deg_i, deg_u, part_i, part_u,
                                              bsum_i, bsum_u, rowptr_i, rowptr_u,
                                              cur_i, cur_u, nbi);
    scatter_k<<<eb2, 256, 0, stream>>>(u_idx, i_idx, cur_i, cur_u, csr_i, csr_u);

    wconv_k<<<(6 * 8192 + 255) / 256, 256, 0, stream>>>(W1, W2, W1t, W2t);
    msg0_k<<<((NUSR + NITM) * 16 + 255) / 256, 256, 0, stream>>>(x_user, x_item,
                                                                 msg_u, msg_i0);

    // ---- 3 layers, each = 1 fused aggemm1 + 1 fused gemm2 ----
    int gI = (NITM + 63) / 64;    // 782 item blocks
    int gU = (NUSR + 63) / 64;    // 1563 user blocks
    const float* cu = x_user;
    const float* ci = x_item;
    __half* msgi = msg_i0;
    __half* msgi_alt = msg_i1;
    for (int l = 0; l < 3; l++) {
        float* ni = xi_buf[l & 1];
        float* nu = xu_buf[l & 1];
        aggemm1f_k<<<gI + gU, 256, 0, stream>>>(
            msgi, msg_u, ci, cu, rowptr_i, rowptr_u, csr_i, csr_u,
            W1t + (size_t)l * 2 * 8192, b1 + (size_t)l * 2 * DD2,
            h1_i, h1_u, gsumAll + l * 2 * 256, gI);
        gemm2f_k<<<gI + gU, 256, 0, stream>>>(
            h1_i, h1_u, gsumAll + l * 2 * 256,
            gamma + (size_t)l * 2 * DD2, beta + (size_t)l * 2 * DD2,
            W2t + (size_t)l * 2 * 8192, b2 + (size_t)l * 2 * DD,
            ni, nu, msgi_alt, msg_u, gI);
        cu = nu; ci = ni;
        __half* tmp = msgi; msgi = msgi_alt; msgi_alt = tmp;
    }

    decode_k<<<(NPRED * 16) / 256, 256, 0, stream>>>(cu, ci, pred, pred + NPRED, out);
}